// Round 3
// baseline (501.565 us; speedup 1.0000x reference)
//
#include <hip/hip_runtime.h>
#include <math.h>

// ---------------------------------------------------------------------------
// KarplusStrong, fully fused single kernel (R8-verified structure).
//   C_t = Wconv3( tf_t ⊙ (C_{t-1} + P_t) ),  P_t = rfft(imps_t)  (spectral
//   recurrence, 3-tap hamming conv, Im=0 at bins 0,256). Contraction =>
//   6-step warmup per 8-frame chunk.
//
// R11: occupancy push. R10 showed dur unchanged at VALUBusy 65% -> 35% of
// cycles are stall (two lgkmcnt drains/iter: Pld write->read, Lc
// write->read) hidden by only 4 waves/SIMD (VGPR=116 and LDS=37.4KB both
// cap at 4). Changes:
//   (a) Merge Pld and LcS into ONE buffer: they are never live at the same
//       time within an iteration (P write+read completes before STEP
//       overwrites; same-wave DS ops are processed in order; no cross-wave
//       sharing). LDS 37.4KB -> 18.5KB  => 8 blocks/CU by LDS.
//   (b) __launch_bounds__(256, 5): min 5 waves/EU => compiler caps VGPRs
//       ~96-102 => 5 waves/SIMD (+25% latency hiding).
// Exchange/numeric structure verbatim from R10 (passed, absmax 7.8e-3).
// ---------------------------------------------------------------------------

#define N_ITER   32768
#define NBINS    257
#define BLOCK_N  512
#define FCH      8
#define NCHUNK   (N_ITER / FCH)     // 4096 waves
#define OUT_LEN  8388608

__device__ __forceinline__ int brev6(int x) { return (int)(__brev((unsigned)x) >> 26); }
__device__ __forceinline__ int PDK(int k) { return k + (k >> 3); }
#define PLDSZ 289

// DPP exchange (VALU, not LDS pipe). CTRL=0xB1: lane^1 (quad_perm);
// 0x4E: lane^2 (quad_perm); 0x128: row_ror:8 == lane^8 within 16-lane rows.
template<int CTRL>
__device__ __forceinline__ float dppq(float x) {
  union { float f; int i; } u; u.f = x;
  u.i = __builtin_amdgcn_update_dpp(u.i, u.i, CTRL, 0xF, 0xF, false);
  return u.f;
}
#define DPP_XOR1 0xB1
#define DPP_XOR2 0x4E
#define DPP_XOR8 0x128

// gfx950 VALU half-wave swaps: partner value z[lane^32] / z[lane^16].
// v_permlane32_swap_b32 returns r[0]=new-vdst={x_lo,x_lo},
// r[1]=new-vsrc={x_hi,x_hi}; partner: lo lanes take r[1], hi take r[0].
__device__ __forceinline__ float pswap32(float x, int lane) {
#if __has_builtin(__builtin_amdgcn_permlane32_swap)
  typedef unsigned v2u __attribute__((ext_vector_type(2)));
  union { float f; unsigned u; } v; v.f = x;
  v2u r = __builtin_amdgcn_permlane32_swap(v.u, v.u, false, false);
  union { unsigned u; float f; } o; o.u = (lane & 32) ? r[0] : r[1];
  return o.f;
#else
  return __shfl_xor(x, 32, 64);
#endif
}
// v_permlane16_swap_b32: r[0] rows={x0,x0,x2,x2}, r[1] rows={x1,x1,x3,x3}.
// Partner x[lane^16]: rows 0,2 take r[1]; rows 1,3 take r[0].
__device__ __forceinline__ float pswap16(float x, int lane) {
#if __has_builtin(__builtin_amdgcn_permlane16_swap)
  typedef unsigned v2u __attribute__((ext_vector_type(2)));
  union { float f; unsigned u; } v; v.f = x;
  v2u r = __builtin_amdgcn_permlane16_swap(v.u, v.u, false, false);
  union { unsigned u; float f; } o; o.u = (lane & 16) ? r[0] : r[1];
  return o.f;
#else
  return __shfl_xor(x, 16, 64);
#endif
}

// 512-pt complex DIF FFT across one wave: reg c, lane l <-> position 64c+l.
// Natural-order input; output at position i holds X[brev9(i)].
// TS=+1: forward (e^-i); TS=-1: inverse kernel (e^+i), unnormalized.
template<int TS>
__device__ __forceinline__ void fft512_regs(float (&zr)[8], float (&zi)[8], int lane) {
  const float ts = (float)TS;
  float s1, c1;
  __sincosf((float)lane * (3.14159265358979323846f / 256.0f), &s1, &c1);
  const float v1r = c1, v1i = -ts * s1;            // e^{-i ts pi l/256}
  const float SQ = 0.70710678118654752f;
  {
    const float r4r[4] = {1.f, SQ, 0.f, -SQ};
    const float r4i[4] = {0.f, -ts*SQ, -ts, -ts*SQ};
    #pragma unroll
    for (int c = 0; c < 4; ++c) {
      float twr = v1r*r4r[c] - v1i*r4i[c];
      float twi = v1r*r4i[c] + v1i*r4r[c];
      float ar = zr[c], ai = zi[c], br = zr[c+4], bi = zi[c+4];
      zr[c] = ar + br; zi[c] = ai + bi;
      float dr = ar - br, di = ai - bi;
      zr[c+4] = dr*twr - di*twi; zi[c+4] = dr*twi + di*twr;
    }
  }
  const float v2r = v1r*v1r - v1i*v1i, v2i = 2.f*v1r*v1i;
  #pragma unroll
  for (int c0 = 0; c0 < 8; c0 += 4) {
    #pragma unroll
    for (int cc = 0; cc < 2; ++cc) {
      int c = c0 + cc;
      float ar = zr[c], ai = zi[c], br = zr[c+2], bi = zi[c+2];
      zr[c] = ar + br; zi[c] = ai + bi;
      float dr = ar - br, di = ai - bi;
      float qr = dr*v2r - di*v2i, qi = dr*v2i + di*v2r;
      if (cc) { float t_ = qr; qr = ts*qi; qi = -ts*t_; }
      zr[c+2] = qr; zi[c+2] = qi;
    }
  }
  float wr = v2r*v2r - v2i*v2i, wi = 2.f*v2r*v2i;
  #pragma unroll
  for (int c = 0; c < 8; c += 2) {
    float ar = zr[c], ai = zi[c], br = zr[c+1], bi = zi[c+1];
    zr[c] = ar + br; zi[c] = ai + bi;
    float dr = ar - br, di = ai - bi;
    zr[c+1] = dr*wr - di*wi; zi[c+1] = dr*wi + di*wr;
  }
  // lane stages m=32..4: chain w; twiddle is -w on hi lanes, so
  // out_hi = (x_hi - x_lo)*w.  m=32/16 via permlane*_swap (VALU),
  // m=8 via DPP row_ror:8 (VALU), m=4 via shuffle (DS pipe).
#define LANE_STAGE(MBIT, EXCH)                                                 \
  {                                                                            \
    float nwr = wr*wr - wi*wi, nwi = 2.f*wr*wi;                                \
    wr = nwr; wi = nwi;                                                        \
    _Pragma("unroll")                                                          \
    for (int c = 0; c < 8; ++c) {                                              \
      float pr_ = EXCH(zr[c]);                                                 \
      float pi_ = EXCH(zi[c]);                                                 \
      bool hi = (lane & (MBIT)) != 0;                                          \
      float sr_ = zr[c] + pr_, si_ = zi[c] + pi_;                              \
      float dr = zr[c] - pr_, di = zi[c] - pi_;                                \
      float qr = dr*wr - di*wi, qi = dr*wi + di*wr;                            \
      zr[c] = hi ? qr : sr_;                                                   \
      zi[c] = hi ? qi : si_;                                                   \
    }                                                                          \
  }
#define EX32(x) pswap32((x), lane)
#define EX16(x) pswap16((x), lane)
#define EX8(x)  dppq<DPP_XOR8>(x)
#define EX4(x)  __shfl_xor((x), 4, 64)
  LANE_STAGE(32, EX32)
  LANE_STAGE(16, EX16)
  LANE_STAGE(8,  EX8)
  LANE_STAGE(4,  EX4)
#undef LANE_STAGE
#undef EX32
#undef EX16
#undef EX8
#undef EX4
  // ---- stage m=2 via DPP quad_perm (xor2) ----
  {
    float nwr = wr*wr - wi*wi, nwi = 2.f*wr*wi;
    wr = nwr; wi = nwi;
    #pragma unroll
    for (int c = 0; c < 8; ++c) {
      float pr_ = dppq<DPP_XOR2>(zr[c]);
      float pi_ = dppq<DPP_XOR2>(zi[c]);
      bool hi = (lane & 2) != 0;
      float sr_ = zr[c] + pr_, si_ = zi[c] + pi_;
      float dr = zr[c] - pr_, di = zi[c] - pi_;
      float qr = dr*wr - di*wi, qi = dr*wi + di*wr;
      zr[c] = hi ? qr : sr_;
      zi[c] = hi ? qi : si_;
    }
  }
  // ---- stage m=1 via DPP quad_perm (xor1), tw = 1 ----
  #pragma unroll
  for (int c = 0; c < 8; ++c) {
    float pr_ = dppq<DPP_XOR1>(zr[c]);
    float pi_ = dppq<DPP_XOR1>(zi[c]);
    bool hi = (lane & 1) != 0;
    zr[c] = hi ? (pr_ - zr[c]) : (zr[c] + pr_);
    zi[c] = hi ? (pi_ - zi[c]) : (zi[c] + pi_);
  }
}

__global__ __launch_bounds__(256, 5) void ks_mega(const float* __restrict__ noise,
                                                  const float* __restrict__ env,
                                                  const float* __restrict__ tfr,
                                                  const float* __restrict__ tfi,
                                                  float* __restrict__ out) {
  // SINGLE shared buffer, time-shared between the P spectra (written+read at
  // iteration start) and the C stash feeding the inverse FFT (written in
  // STEP, read right after). Safe: same-wave DS ops process in order; no
  // cross-wave sharing; P reads complete (lgkmcnt) before STEP's overwrites
  // are issued... (in-order DS pipe per wave guarantees read-before-write
  // even without the wait). Halves LDS: 37.4KB -> 18.5KB.
  __shared__ float2 Pld[4][2][PLDSZ];
  const int w = threadIdx.x >> 6, lane = threadIdx.x & 63;
  const int j = blockIdx.x * 4 + w;
  const int k0 = lane * 4;
  const bool l63 = (lane == 63);
  const int rr = brev6(lane);
  const int base = 8 * rr;
  const int tprod = j * FCH;
  const int t0 = (j == 0) ? 0 : (tprod - 6);
  const int tend = tprod + FCH;
  float2* Pw0 = &Pld[w][0][0];
  float2* Pw1 = &Pld[w][1][0];
  float2* Lc0 = Pw0;                 // aliased on purpose (see header comment)
  float2* Lc1 = Pw1;
  const float sc = 1.0f / 512.0f;
  const int CB3[8] = {0,4,2,6,1,5,3,7};

  float Cr[4] = {0.f,0.f,0.f,0.f}, Ci[4] = {0.f,0.f,0.f,0.f};
  float C256 = 0.f;
  float tr[2][4], ti[2][4];
  float t6r[2] = {0.f,0.f}, t6i[2] = {0.f,0.f};
  float nA[8], nB[8], eA, eB;
  float pvb[8] = {0.f,0.f,0.f,0.f,0.f,0.f,0.f,0.f};

  // j==0 pre-pair: frame -1 = 0, frame 0 = imps0 (zero spectrum). Emit row 0
  // (= imps0 lower half) and seed pvb with frame 0.
  if (j == 0) {
    const float e0 = env[0]; const float e02 = e0 * e0;
    const float* n0 = noise + base;
    float q[8];
    *(float4*)(&q[0]) = *(const float4*)(n0);
    *(float4*)(&q[4]) = *(const float4*)(n0 + 4);
    #pragma unroll
    for (int s = 0; s < 8; ++s) pvb[s] = (2.f * q[s] - 1.f) * e02;
    if (!(lane & 1)) {
      float* o = out + base;
      ((float4*)o)[0] = make_float4(pvb[0], pvb[1], pvb[2], pvb[3]);
      ((float4*)o)[1] = make_float4(pvb[4], pvb[5], pvb[6], pvb[7]);
    }
  }

#define LOADTF(S, TS_) do {                                                    \
    const size_t _bt = (size_t)(TS_) * NBINS;                                  \
    _Pragma("unroll") for (int _i = 0; _i < 4; ++_i) {                         \
      tr[S][_i] = tfr[_bt + k0 + _i];                                          \
      ti[S][_i] = tfi[_bt + k0 + _i];                                          \
    }                                                                          \
    if (l63) { t6r[S] = tfr[_bt + 256]; t6i[S] = tfi[_bt + 256]; }             \
  } while (0)

#define LOADNOISE(TA, TB) do {                                                 \
    const float* _pa = noise + (size_t)(TA) * BLOCK_N;                         \
    const float* _pb = noise + (size_t)(TB) * BLOCK_N;                         \
    _Pragma("unroll") for (int _c = 0; _c < 8; ++_c) {                         \
      nA[_c] = _pa[64*_c + lane];                                              \
      nB[_c] = _pb[64*_c + lane];                                              \
    }                                                                          \
    eA = env[TA]; eB = env[TB];                                                \
  } while (0)

// One recurrence step; stash C_t to LDS (recur layout) when it will feed an
// inverse FFT (t >= tprod-2).
#define STEP(S, T, PR, PI, P6R, P6I) do {                                      \
    const int _t = (T);                                                        \
    float Vr[4], Vi[4];                                                        \
    _Pragma("unroll") for (int _i = 0; _i < 4; ++_i) {                         \
      float Ur = Cr[_i] + PR[_i], Ui = Ci[_i] + PI[_i];                        \
      Vr[_i] = tr[S][_i]*Ur - ti[S][_i]*Ui;                                    \
      Vi[_i] = tr[S][_i]*Ui + ti[S][_i]*Ur;                                    \
    }                                                                          \
    if (lane == 0) Vi[0] = 0.f;                                                \
    float U6r = C256 + P6R, U6i = P6I;                                         \
    float V6r = t6r[S]*U6r - t6i[S]*U6i;                                       \
    int _tf = _t + 2; if (_tf > N_ITER - 1) _tf = N_ITER - 1;                  \
    LOADTF(S, _tf);                                                            \
    float Lr = __shfl_up(Vr[3], 1),   Li = __shfl_up(Vi[3], 1);                \
    float Rr = __shfl_down(Vr[0], 1), Ri = __shfl_down(Vi[0], 1);              \
    if (lane == 0) { Lr = Vr[1]; Li = -Vi[1]; }                                \
    if (l63)       { Rr = V6r;   Ri = 0.f; }                                   \
    Cr[0] = 0.54f*Vr[0] - 0.23f*(Lr    + Vr[1]);                               \
    Ci[0] = 0.54f*Vi[0] - 0.23f*(Li    + Vi[1]);                               \
    Cr[1] = 0.54f*Vr[1] - 0.23f*(Vr[0] + Vr[2]);                               \
    Ci[1] = 0.54f*Vi[1] - 0.23f*(Vi[0] + Vi[2]);                               \
    Cr[2] = 0.54f*Vr[2] - 0.23f*(Vr[1] + Vr[3]);                               \
    Ci[2] = 0.54f*Vi[2] - 0.23f*(Vi[1] + Vi[3]);                               \
    Cr[3] = 0.54f*Vr[3] - 0.23f*(Vr[2] + Rr);                                  \
    Ci[3] = 0.54f*Vi[3] - 0.23f*(Vi[2] + Ri);                                  \
    C256  = 0.54f*V6r   - 0.46f*Vr[3];                                         \
    if (_t >= tprod - 2) {                                                     \
      float2* _Ls = ((_t) & 1) ? Lc1 : Lc0;                                    \
      _Ls[PDK(k0 + 0)] = make_float2(Cr[0], Ci[0]);                            \
      _Ls[PDK(k0 + 1)] = make_float2(Cr[1], Ci[1]);                            \
      _Ls[PDK(k0 + 2)] = make_float2(Cr[2], Ci[2]);                            \
      _Ls[PDK(k0 + 3)] = make_float2(Cr[3], Ci[3]);                            \
      if (l63) _Ls[PDK(256)] = make_float2(C256, 0.f);                         \
    }                                                                          \
  } while (0)

  LOADTF(0, t0);
  LOADTF(1, t0 + 1);
  LOADNOISE(t0, t0 + 1);

  for (int t = t0; t < tend; t += 2) {
    // ---- packed forward FFT of impulses (t, t+1) ----
    const float ea2 = eA * eA, eb2 = eB * eB;
    float zr[8], zi[8];
    #pragma unroll
    for (int c = 0; c < 8; ++c) {
      zr[c] = (2.f * nA[c] - 1.f) * ea2;
      zi[c] = (2.f * nB[c] - 1.f) * eb2;
    }
    {
      int ta = t + 2; if (ta > N_ITER - 1) ta = N_ITER - 1;
      int tb = t + 3; if (tb > N_ITER - 1) tb = N_ITER - 1;
      LOADNOISE(ta, tb);
    }
    fft512_regs<1>(zr, zi, lane);
    float mr[8], mi[8];
    {
      int r_ = brev6(lane);
      int lam = brev6((64 - r_) & 63);
      mr[0] = __shfl(zr[0], lam, 64); mi[0] = __shfl(zi[0], lam, 64);
    }
    mr[1] = __shfl_xor(zr[1], 63, 64); mi[1] = __shfl_xor(zi[1], 63, 64);
    mr[2] = __shfl_xor(zr[3], 63, 64); mi[2] = __shfl_xor(zi[3], 63, 64);
    mr[3] = __shfl_xor(zr[2], 63, 64); mi[3] = __shfl_xor(zi[2], 63, 64);
    mr[4] = __shfl_xor(zr[7], 63, 64); mi[4] = __shfl_xor(zi[7], 63, 64);
    mr[5] = __shfl_xor(zr[6], 63, 64); mi[5] = __shfl_xor(zi[6], 63, 64);
    mr[6] = __shfl_xor(zr[5], 63, 64); mi[6] = __shfl_xor(zi[5], 63, 64);
    mr[7] = __shfl_xor(zr[4], 63, 64); mi[7] = __shfl_xor(zi[4], 63, 64);
    if (!(lane & 1)) {
      #pragma unroll
      for (int s = 0; s < 8; ++s) {
        int c = CB3[s];
        int k = 8 * rr + s;
        Pw0[PDK(k)] = make_float2(0.5f*(zr[c] + mr[c]), 0.5f*(zi[c] - mi[c]));
        Pw1[PDK(k)] = make_float2(0.5f*(zi[c] + mi[c]), 0.5f*(mr[c] - zr[c]));
      }
    } else if (lane == 1) {
      Pw0[PDK(256)] = make_float2(0.5f*(zr[0] + mr[0]), 0.5f*(zi[0] - mi[0]));
      Pw1[PDK(256)] = make_float2(0.5f*(zi[0] + mi[0]), 0.5f*(mr[0] - zr[0]));
    }
    float pr0[4], pi0[4], pr1[4], pi1[4];
    float p60r = 0.f, p60i = 0.f, p61r = 0.f, p61i = 0.f;
    #pragma unroll
    for (int i = 0; i < 4; ++i) {
      float2 q0 = Pw0[PDK(k0 + i)];
      float2 q1 = Pw1[PDK(k0 + i)];
      pr0[i] = q0.x; pi0[i] = q0.y;
      pr1[i] = q1.x; pi1[i] = q1.y;
    }
    if (l63) {
      float2 q0 = Pw0[PDK(256)]; p60r = q0.x; p60i = q0.y;
      float2 q1 = Pw1[PDK(256)]; p61r = q1.x; p61i = q1.y;
    }
    // ---- two recurrence steps (stash C to LDS when inv-active) ----
    STEP(0, t,     pr0, pi0, p60r, p60i);
    STEP(1, t + 1, pr1, pi1, p61r, p61i);
    // ---- packed inverse FFT of (C[t], C[t+1]) -> frames (t+1, t+2) ----
    if (t >= tprod - 2) {
      float izr[8], izi[8];
      #pragma unroll
      for (int c = 0; c < 8; ++c) {
        int k = 64 * c + lane;
        bool mir = (k > 256);
        int idx = mir ? (512 - k) : k;
        float2 a = Lc0[PDK(idx)];
        float2 b = Lc1[PDK(idx)];
        float ay = mir ? -a.y : a.y;
        float by = mir ?  b.y : -b.y;
        izr[c] = sc * (a.x + by);
        izi[c] = sc * (b.x + ay);
      }
      fft512_regs<-1>(izr, izi, lane);
      const int fa = t + 1;
      int fb = t + 2; int nfb = (fb > N_ITER - 1) ? (N_ITER - 1) : fb;
      const float efa = env[fa];  const float efa2 = efa * efa;
      const float efb = env[nfb]; const float efb2 = efb * efb;
      const float* na_ = noise + (size_t)fa  * BLOCK_N + base;
      const float* nb_ = noise + (size_t)nfb * BLOCK_N + base;
      float Aa[8], Bb[8];
      *(float4*)(&Aa[0]) = *(const float4*)(na_);
      *(float4*)(&Aa[4]) = *(const float4*)(na_ + 4);
      *(float4*)(&Bb[0]) = *(const float4*)(nb_);
      *(float4*)(&Bb[4]) = *(const float4*)(nb_ + 4);
      float va[8], vb[8];
      #pragma unroll
      for (int s = 0; s < 8; ++s) {
        int c = CB3[s];
        va[s] = izr[c] + (2.f * Aa[s] - 1.f) * efa2;
        vb[s] = izi[c] + (2.f * Bb[s] - 1.f) * efb2;
      }
      // Half-merge exchanges via DPP xor1 (VALU, replaces 16 bpermutes).
      float sva[8], spv[8];
      #pragma unroll
      for (int s = 0; s < 8; ++s) {
        sva[s] = dppq<DPP_XOR1>(va[s]);
        spv[s] = dppq<DPP_XOR1>(pvb[s]);
      }
      if (!(lane & 1)) {
        if (t >= tprod) {                       // row fa = va lower + pvb upper
          float* o = out + (size_t)fa * 256 + base;
          ((float4*)o)[0] = make_float4(va[0]+spv[0], va[1]+spv[1], va[2]+spv[2], va[3]+spv[3]);
          ((float4*)o)[1] = make_float4(va[4]+spv[4], va[5]+spv[5], va[6]+spv[6], va[7]+spv[7]);
        }
        if (fb <= tprod + 7) {                  // row fb = vb lower + va upper
          float* o = out + (size_t)fb * 256 + base;
          ((float4*)o)[0] = make_float4(vb[0]+sva[0], vb[1]+sva[1], vb[2]+sva[2], vb[3]+sva[3]);
          ((float4*)o)[1] = make_float4(vb[4]+sva[4], vb[5]+sva[5], vb[6]+sva[6], vb[7]+sva[7]);
        }
      }
      #pragma unroll
      for (int s = 0; s < 8; ++s) pvb[s] = vb[s];
    }
  }
#undef LOADTF
#undef LOADNOISE
#undef STEP
}

extern "C" void kernel_launch(void* const* d_in, const int* in_sizes, int n_in,
                              void* d_out, int out_size, void* d_ws, size_t ws_size,
                              hipStream_t stream) {
  (void)in_sizes; (void)n_in; (void)ws_size; (void)out_size; (void)d_ws;
  const float* noise = (const float*)d_in[1];
  const float* env   = (const float*)d_in[2];
  const float* tfr   = (const float*)d_in[3];
  const float* tfi   = (const float*)d_in[4];
  float* out = (float*)d_out;
  // Single fused kernel; no workspace needed (every out row fully written).
  ks_mega<<<dim3(NCHUNK / 4), dim3(256), 0, stream>>>(noise, env, tfr, tfi, out);
}

// Round 5
// 248.869 us; speedup vs baseline: 2.0154x; 2.0154x over previous
//
#include <hip/hip_runtime.h>
#include <math.h>

// ---------------------------------------------------------------------------
// KarplusStrong, fully fused single kernel.
//   C_t = Wconv3( tf_t ⊙ (C_{t-1} + P_t) ),  P_t = rfft(imps_t)  (spectral
//   recurrence, 3-tap hamming conv, Im=0 at bins 0,256). Contraction =>
//   6-step warmup per 8-frame chunk.
//
// R13 == R12 resubmitted verbatim (R12 bench died on infra: "container
// failed twice"; no counters to learn from).
//
// R12: software-pipelined forward FFT for stall coverage.
//  - R11 post-mortem: launch_bounds(256,5) forced VGPR=48 -> catastrophic
//    scratch spill (FETCH 150->662MB, 399us). REVERTED to plain (256).
//    The Pld/Lc LDS merge (18.5KB) PASSED and is kept (same-wave DS ops are
//    processed in order, so aliasing P and Lc is safe in program order).
//  - R10 analysis: VALUBusy 65%, 4 waves/SIMD; ~35% of cycles are the two
//    LDS write->read drains per iteration (P merge->read, Lc stash->read)
//    with nothing to cover them. Fix: carry z = fft(imps(t+2)) across the
//    loop. Loop order: [merge z->P(t)] [imps(t+2)] [FFT HEAD: VALU-only,
//    covers P write->read] [read P] [STEP x2 -> Lc] [noise prefetch t+4]
//    [FFT TAIL m=4/2/1: covers Lc write->read] [invFFT + epilogue].
//    One wasted fwd FFT per wave (last iter) keeps cover uniform.
// ---------------------------------------------------------------------------

#define N_ITER   32768
#define NBINS    257
#define BLOCK_N  512
#define FCH      8
#define NCHUNK   (N_ITER / FCH)     // 4096 waves
#define OUT_LEN  8388608

__device__ __forceinline__ int brev6(int x) { return (int)(__brev((unsigned)x) >> 26); }
__device__ __forceinline__ int PDK(int k) { return k + (k >> 3); }
#define PLDSZ 289

// DPP exchange (VALU, not LDS pipe). CTRL=0xB1: lane^1 (quad_perm);
// 0x4E: lane^2 (quad_perm); 0x128: row_ror:8 == lane^8 within 16-lane rows.
template<int CTRL>
__device__ __forceinline__ float dppq(float x) {
  union { float f; int i; } u; u.f = x;
  u.i = __builtin_amdgcn_update_dpp(u.i, u.i, CTRL, 0xF, 0xF, false);
  return u.f;
}
#define DPP_XOR1 0xB1
#define DPP_XOR2 0x4E
#define DPP_XOR8 0x128

// gfx950 VALU half-wave swaps: partner value z[lane^32] / z[lane^16].
// v_permlane32_swap_b32 returns r[0]=new-vdst={x_lo,x_lo},
// r[1]=new-vsrc={x_hi,x_hi}; partner: lo lanes take r[1], hi take r[0].
__device__ __forceinline__ float pswap32(float x, int lane) {
#if __has_builtin(__builtin_amdgcn_permlane32_swap)
  typedef unsigned v2u __attribute__((ext_vector_type(2)));
  union { float f; unsigned u; } v; v.f = x;
  v2u r = __builtin_amdgcn_permlane32_swap(v.u, v.u, false, false);
  union { unsigned u; float f; } o; o.u = (lane & 32) ? r[0] : r[1];
  return o.f;
#else
  return __shfl_xor(x, 32, 64);
#endif
}
// v_permlane16_swap_b32: r[0] rows={x0,x0,x2,x2}, r[1] rows={x1,x1,x3,x3}.
// Partner x[lane^16]: rows 0,2 take r[1]; rows 1,3 take r[0].
__device__ __forceinline__ float pswap16(float x, int lane) {
#if __has_builtin(__builtin_amdgcn_permlane16_swap)
  typedef unsigned v2u __attribute__((ext_vector_type(2)));
  union { float f; unsigned u; } v; v.f = x;
  v2u r = __builtin_amdgcn_permlane16_swap(v.u, v.u, false, false);
  union { unsigned u; float f; } o; o.u = (lane & 16) ? r[0] : r[1];
  return o.f;
#else
  return __shfl_xor(x, 16, 64);
#endif
}

// 512-pt complex DIF FFT across one wave: reg c, lane l <-> position 64c+l.
// Natural-order input; output at position i holds X[brev9(i)].
// TS=+1: forward (e^-i); TS=-1: inverse kernel (e^+i), unnormalized.
// Split into head (reg stages + m=32/16/8, VALU-only) and tail (m=4 DS,
// m=2/1 DPP) so the caller can interleave LDS round-trips between them.

#define LANE_STAGE(MBIT, EXCH)                                                 \
  {                                                                            \
    float nwr = wr*wr - wi*wi, nwi = 2.f*wr*wi;                                \
    wr = nwr; wi = nwi;                                                        \
    _Pragma("unroll")                                                          \
    for (int c = 0; c < 8; ++c) {                                              \
      float pr_ = EXCH(zr[c]);                                                 \
      float pi_ = EXCH(zi[c]);                                                 \
      bool hi = (lane & (MBIT)) != 0;                                          \
      float sr_ = zr[c] + pr_, si_ = zi[c] + pi_;                              \
      float dr = zr[c] - pr_, di = zi[c] - pi_;                                \
      float qr = dr*wr - di*wi, qi = dr*wi + di*wr;                            \
      zr[c] = hi ? qr : sr_;                                                   \
      zi[c] = hi ? qi : si_;                                                   \
    }                                                                          \
  }
#define EX32(x) pswap32((x), lane)
#define EX16(x) pswap16((x), lane)
#define EX8(x)  dppq<DPP_XOR8>(x)
#define EX4(x)  __shfl_xor((x), 4, 64)

template<int TS>
__device__ __forceinline__ void fft512_head(float (&zr)[8], float (&zi)[8], int lane,
                                            float &wr, float &wi) {
  const float ts = (float)TS;
  float s1, c1;
  __sincosf((float)lane * (3.14159265358979323846f / 256.0f), &s1, &c1);
  const float v1r = c1, v1i = -ts * s1;            // e^{-i ts pi l/256}
  const float SQ = 0.70710678118654752f;
  {
    const float r4r[4] = {1.f, SQ, 0.f, -SQ};
    const float r4i[4] = {0.f, -ts*SQ, -ts, -ts*SQ};
    #pragma unroll
    for (int c = 0; c < 4; ++c) {
      float twr = v1r*r4r[c] - v1i*r4i[c];
      float twi = v1r*r4i[c] + v1i*r4r[c];
      float ar = zr[c], ai = zi[c], br = zr[c+4], bi = zi[c+4];
      zr[c] = ar + br; zi[c] = ai + bi;
      float dr = ar - br, di = ai - bi;
      zr[c+4] = dr*twr - di*twi; zi[c+4] = dr*twi + di*twr;
    }
  }
  const float v2r = v1r*v1r - v1i*v1i, v2i = 2.f*v1r*v1i;
  #pragma unroll
  for (int c0 = 0; c0 < 8; c0 += 4) {
    #pragma unroll
    for (int cc = 0; cc < 2; ++cc) {
      int c = c0 + cc;
      float ar = zr[c], ai = zi[c], br = zr[c+2], bi = zi[c+2];
      zr[c] = ar + br; zi[c] = ai + bi;
      float dr = ar - br, di = ai - bi;
      float qr = dr*v2r - di*v2i, qi = dr*v2i + di*v2r;
      if (cc) { float t_ = qr; qr = ts*qi; qi = -ts*t_; }
      zr[c+2] = qr; zi[c+2] = qi;
    }
  }
  wr = v2r*v2r - v2i*v2i; wi = 2.f*v2r*v2i;
  #pragma unroll
  for (int c = 0; c < 8; c += 2) {
    float ar = zr[c], ai = zi[c], br = zr[c+1], bi = zi[c+1];
    zr[c] = ar + br; zi[c] = ai + bi;
    float dr = ar - br, di = ai - bi;
    zr[c+1] = dr*wr - di*wi; zi[c+1] = dr*wi + di*wr;
  }
  LANE_STAGE(32, EX32)
  LANE_STAGE(16, EX16)
  LANE_STAGE(8,  EX8)
}

template<int TS>
__device__ __forceinline__ void fft512_tail(float (&zr)[8], float (&zi)[8], int lane,
                                            float &wr, float &wi) {
  LANE_STAGE(4, EX4)
  // ---- stage m=2 via DPP quad_perm (xor2) ----
  {
    float nwr = wr*wr - wi*wi, nwi = 2.f*wr*wi;
    wr = nwr; wi = nwi;
    #pragma unroll
    for (int c = 0; c < 8; ++c) {
      float pr_ = dppq<DPP_XOR2>(zr[c]);
      float pi_ = dppq<DPP_XOR2>(zi[c]);
      bool hi = (lane & 2) != 0;
      float sr_ = zr[c] + pr_, si_ = zi[c] + pi_;
      float dr = zr[c] - pr_, di = zi[c] - pi_;
      float qr = dr*wr - di*wi, qi = dr*wi + di*wr;
      zr[c] = hi ? qr : sr_;
      zi[c] = hi ? qi : si_;
    }
  }
  // ---- stage m=1 via DPP quad_perm (xor1), tw = 1 ----
  #pragma unroll
  for (int c = 0; c < 8; ++c) {
    float pr_ = dppq<DPP_XOR1>(zr[c]);
    float pi_ = dppq<DPP_XOR1>(zi[c]);
    bool hi = (lane & 1) != 0;
    zr[c] = hi ? (pr_ - zr[c]) : (zr[c] + pr_);
    zi[c] = hi ? (pi_ - zi[c]) : (zi[c] + pi_);
  }
}

template<int TS>
__device__ __forceinline__ void fft512_regs(float (&zr)[8], float (&zi)[8], int lane) {
  float wr, wi;
  fft512_head<TS>(zr, zi, lane, wr, wi);
  fft512_tail<TS>(zr, zi, lane, wr, wi);
}

#undef LANE_STAGE
#undef EX32
#undef EX16
#undef EX8
#undef EX4

__global__ __launch_bounds__(256) void ks_mega(const float* __restrict__ noise,
                                               const float* __restrict__ env,
                                               const float* __restrict__ tfr,
                                               const float* __restrict__ tfi,
                                               float* __restrict__ out) {
  // SINGLE shared buffer, time-shared between the P spectra and the C stash
  // (R11-verified: same-wave DS ops process in order; P write->read and Lc
  // write->read never interleave wrongly in program order, incl. the R12
  // reordering: P(t)w, P(t)r, Lc(t)w, Lc(t)r, P(t+2)w, ...).
  __shared__ float2 Pld[4][2][PLDSZ];
  const int w = threadIdx.x >> 6, lane = threadIdx.x & 63;
  const int j = blockIdx.x * 4 + w;
  const int k0 = lane * 4;
  const bool l63 = (lane == 63);
  const int rr = brev6(lane);
  const int base = 8 * rr;
  const int tprod = j * FCH;
  const int t0 = (j == 0) ? 0 : (tprod - 6);
  const int tend = tprod + FCH;
  float2* Pw0 = &Pld[w][0][0];
  float2* Pw1 = &Pld[w][1][0];
  float2* Lc0 = Pw0;                 // aliased on purpose (see above)
  float2* Lc1 = Pw1;
  const float sc = 1.0f / 512.0f;
  const int CB3[8] = {0,4,2,6,1,5,3,7};

  float Cr[4] = {0.f,0.f,0.f,0.f}, Ci[4] = {0.f,0.f,0.f,0.f};
  float C256 = 0.f;
  float tr[2][4], ti[2][4];
  float t6r[2] = {0.f,0.f}, t6i[2] = {0.f,0.f};
  float nA[8], nB[8], eA, eB;
  float pvb[8] = {0.f,0.f,0.f,0.f,0.f,0.f,0.f,0.f};

  // j==0 pre-pair: frame -1 = 0, frame 0 = imps0 (zero spectrum). Emit row 0
  // (= imps0 lower half) and seed pvb with frame 0.
  if (j == 0) {
    const float e0 = env[0]; const float e02 = e0 * e0;
    const float* n0 = noise + base;
    float q[8];
    *(float4*)(&q[0]) = *(const float4*)(n0);
    *(float4*)(&q[4]) = *(const float4*)(n0 + 4);
    #pragma unroll
    for (int s = 0; s < 8; ++s) pvb[s] = (2.f * q[s] - 1.f) * e02;
    if (!(lane & 1)) {
      float* o = out + base;
      ((float4*)o)[0] = make_float4(pvb[0], pvb[1], pvb[2], pvb[3]);
      ((float4*)o)[1] = make_float4(pvb[4], pvb[5], pvb[6], pvb[7]);
    }
  }

#define LOADTF(S, TS_) do {                                                    \
    const size_t _bt = (size_t)(TS_) * NBINS;                                  \
    _Pragma("unroll") for (int _i = 0; _i < 4; ++_i) {                         \
      tr[S][_i] = tfr[_bt + k0 + _i];                                          \
      ti[S][_i] = tfi[_bt + k0 + _i];                                          \
    }                                                                          \
    if (l63) { t6r[S] = tfr[_bt + 256]; t6i[S] = tfi[_bt + 256]; }             \
  } while (0)

#define LOADNOISE(TA, TB) do {                                                 \
    const float* _pa = noise + (size_t)(TA) * BLOCK_N;                         \
    const float* _pb = noise + (size_t)(TB) * BLOCK_N;                         \
    _Pragma("unroll") for (int _c = 0; _c < 8; ++_c) {                         \
      nA[_c] = _pa[64*_c + lane];                                              \
      nB[_c] = _pb[64*_c + lane];                                              \
    }                                                                          \
    eA = env[TA]; eB = env[TB];                                                \
  } while (0)

// One recurrence step; stash C_t to LDS (recur layout) when it will feed an
// inverse FFT (t >= tprod-2).
#define STEP(S, T, PR, PI, P6R, P6I) do {                                      \
    const int _t = (T);                                                        \
    float Vr[4], Vi[4];                                                        \
    _Pragma("unroll") for (int _i = 0; _i < 4; ++_i) {                         \
      float Ur = Cr[_i] + PR[_i], Ui = Ci[_i] + PI[_i];                        \
      Vr[_i] = tr[S][_i]*Ur - ti[S][_i]*Ui;                                    \
      Vi[_i] = tr[S][_i]*Ui + ti[S][_i]*Ur;                                    \
    }                                                                          \
    if (lane == 0) Vi[0] = 0.f;                                                \
    float U6r = C256 + P6R, U6i = P6I;                                         \
    float V6r = t6r[S]*U6r - t6i[S]*U6i;                                       \
    int _tf = _t + 2; if (_tf > N_ITER - 1) _tf = N_ITER - 1;                  \
    LOADTF(S, _tf);                                                            \
    float Lr = __shfl_up(Vr[3], 1),   Li = __shfl_up(Vi[3], 1);                \
    float Rr = __shfl_down(Vr[0], 1), Ri = __shfl_down(Vi[0], 1);              \
    if (lane == 0) { Lr = Vr[1]; Li = -Vi[1]; }                                \
    if (l63)       { Rr = V6r;   Ri = 0.f; }                                   \
    Cr[0] = 0.54f*Vr[0] - 0.23f*(Lr    + Vr[1]);                               \
    Ci[0] = 0.54f*Vi[0] - 0.23f*(Li    + Vi[1]);                               \
    Cr[1] = 0.54f*Vr[1] - 0.23f*(Vr[0] + Vr[2]);                               \
    Ci[1] = 0.54f*Vi[1] - 0.23f*(Vi[0] + Vi[2]);                               \
    Cr[2] = 0.54f*Vr[2] - 0.23f*(Vr[1] + Vr[3]);                               \
    Ci[2] = 0.54f*Vi[2] - 0.23f*(Vi[1] + Vi[3]);                               \
    Cr[3] = 0.54f*Vr[3] - 0.23f*(Vr[2] + Rr);                                  \
    Ci[3] = 0.54f*Vi[3] - 0.23f*(Vi[2] + Ri);                                  \
    C256  = 0.54f*V6r   - 0.46f*Vr[3];                                         \
    if (_t >= tprod - 2) {                                                     \
      float2* _Ls = ((_t) & 1) ? Lc1 : Lc0;                                    \
      _Ls[PDK(k0 + 0)] = make_float2(Cr[0], Ci[0]);                            \
      _Ls[PDK(k0 + 1)] = make_float2(Cr[1], Ci[1]);                            \
      _Ls[PDK(k0 + 2)] = make_float2(Cr[2], Ci[2]);                            \
      _Ls[PDK(k0 + 3)] = make_float2(Cr[3], Ci[3]);                            \
      if (l63) _Ls[PDK(256)] = make_float2(C256, 0.f);                         \
    }                                                                          \
  } while (0)

  LOADTF(0, t0);
  LOADTF(1, t0 + 1);

  // Prologue: z = fft(imps(t0, t0+1)) computed directly; then prefetch
  // noise for pair t0+2 into nA/nB.
  float zr[8], zi[8];
  {
    const float* p0 = noise + (size_t)t0 * BLOCK_N;
    const float* p1 = noise + (size_t)(t0 + 1) * BLOCK_N;
    const float e0 = env[t0], e1 = env[t0 + 1];
    const float e02 = e0 * e0, e12 = e1 * e1;
    #pragma unroll
    for (int c = 0; c < 8; ++c) {
      zr[c] = (2.f * p0[64*c + lane] - 1.f) * e02;
      zi[c] = (2.f * p1[64*c + lane] - 1.f) * e12;
    }
    fft512_regs<1>(zr, zi, lane);
  }
  {
    int ta = t0 + 2; if (ta > N_ITER - 1) ta = N_ITER - 1;
    int tb = t0 + 3; if (tb > N_ITER - 1) tb = N_ITER - 1;
    LOADNOISE(ta, tb);
  }

  for (int t = t0; t < tend; t += 2) {
    // ---- 1. hermitian merge of z = fft(imps(t,t+1)) -> P(t) LDS writes ----
    float mr[8], mi[8];
    {
      int r_ = brev6(lane);
      int lam = brev6((64 - r_) & 63);
      mr[0] = __shfl(zr[0], lam, 64); mi[0] = __shfl(zi[0], lam, 64);
    }
    mr[1] = __shfl_xor(zr[1], 63, 64); mi[1] = __shfl_xor(zi[1], 63, 64);
    mr[2] = __shfl_xor(zr[3], 63, 64); mi[2] = __shfl_xor(zi[3], 63, 64);
    mr[3] = __shfl_xor(zr[2], 63, 64); mi[3] = __shfl_xor(zi[2], 63, 64);
    mr[4] = __shfl_xor(zr[7], 63, 64); mi[4] = __shfl_xor(zi[7], 63, 64);
    mr[5] = __shfl_xor(zr[6], 63, 64); mi[5] = __shfl_xor(zi[6], 63, 64);
    mr[6] = __shfl_xor(zr[5], 63, 64); mi[6] = __shfl_xor(zi[5], 63, 64);
    mr[7] = __shfl_xor(zr[4], 63, 64); mi[7] = __shfl_xor(zi[4], 63, 64);
    if (!(lane & 1)) {
      #pragma unroll
      for (int s = 0; s < 8; ++s) {
        int c = CB3[s];
        int k = 8 * rr + s;
        Pw0[PDK(k)] = make_float2(0.5f*(zr[c] + mr[c]), 0.5f*(zi[c] - mi[c]));
        Pw1[PDK(k)] = make_float2(0.5f*(zi[c] + mi[c]), 0.5f*(mr[c] - zr[c]));
      }
    } else if (lane == 1) {
      Pw0[PDK(256)] = make_float2(0.5f*(zr[0] + mr[0]), 0.5f*(zi[0] - mi[0]));
      Pw1[PDK(256)] = make_float2(0.5f*(zi[0] + mi[0]), 0.5f*(mr[0] - zr[0]));
    }
    // ---- 2. imps(t+2, t+3) from prefetched noise (overwrites z) ----
    {
      const float ea2 = eA * eA, eb2 = eB * eB;
      #pragma unroll
      for (int c = 0; c < 8; ++c) {
        zr[c] = (2.f * nA[c] - 1.f) * ea2;
        zi[c] = (2.f * nB[c] - 1.f) * eb2;
      }
    }
    // ---- 3. fwd FFT HEAD (VALU-only): covers P write->read latency ----
    float wr_, wi_;
    fft512_head<1>(zr, zi, lane, wr_, wi_);
    // ---- 4. read P(t) ----
    float pr0[4], pi0[4], pr1[4], pi1[4];
    float p60r = 0.f, p60i = 0.f, p61r = 0.f, p61i = 0.f;
    #pragma unroll
    for (int i = 0; i < 4; ++i) {
      float2 q0 = Pw0[PDK(k0 + i)];
      float2 q1 = Pw1[PDK(k0 + i)];
      pr0[i] = q0.x; pi0[i] = q0.y;
      pr1[i] = q1.x; pi1[i] = q1.y;
    }
    if (l63) {
      float2 q0 = Pw0[PDK(256)]; p60r = q0.x; p60i = q0.y;
      float2 q1 = Pw1[PDK(256)]; p61r = q1.x; p61i = q1.y;
    }
    // ---- 5. two recurrence steps (stash C to LDS when inv-active) ----
    STEP(0, t,     pr0, pi0, p60r, p60i);
    STEP(1, t + 1, pr1, pi1, p61r, p61i);
    // ---- 5.5 noise prefetch for pair t+4 (consumed next iter step 2) ----
    {
      int ta = t + 4; if (ta > N_ITER - 1) ta = N_ITER - 1;
      int tb = t + 5; if (tb > N_ITER - 1) tb = N_ITER - 1;
      LOADNOISE(ta, tb);
    }
    // ---- 6. fwd FFT TAIL (m=4/2/1): covers Lc write->read latency ----
    fft512_tail<1>(zr, zi, lane, wr_, wi_);
    // ---- 7-10. packed inverse FFT of (C[t], C[t+1]) -> frames (t+1,t+2) ----
    if (t >= tprod - 2) {
      float izr[8], izi[8];
      #pragma unroll
      for (int c = 0; c < 8; ++c) {
        int k = 64 * c + lane;
        bool mir = (k > 256);
        int idx = mir ? (512 - k) : k;
        float2 a = Lc0[PDK(idx)];
        float2 b = Lc1[PDK(idx)];
        float ay = mir ? -a.y : a.y;
        float by = mir ?  b.y : -b.y;
        izr[c] = sc * (a.x + by);
        izi[c] = sc * (b.x + ay);
      }
      fft512_regs<-1>(izr, izi, lane);
      const int fa = t + 1;
      int fb = t + 2; int nfb = (fb > N_ITER - 1) ? (N_ITER - 1) : fb;
      const float efa = env[fa];  const float efa2 = efa * efa;
      const float efb = env[nfb]; const float efb2 = efb * efb;
      const float* na_ = noise + (size_t)fa  * BLOCK_N + base;
      const float* nb_ = noise + (size_t)nfb * BLOCK_N + base;
      float Aa[8], Bb[8];
      *(float4*)(&Aa[0]) = *(const float4*)(na_);
      *(float4*)(&Aa[4]) = *(const float4*)(na_ + 4);
      *(float4*)(&Bb[0]) = *(const float4*)(nb_);
      *(float4*)(&Bb[4]) = *(const float4*)(nb_ + 4);
      float va[8], vb[8];
      #pragma unroll
      for (int s = 0; s < 8; ++s) {
        int c = CB3[s];
        va[s] = izr[c] + (2.f * Aa[s] - 1.f) * efa2;
        vb[s] = izi[c] + (2.f * Bb[s] - 1.f) * efb2;
      }
      // Half-merge exchanges via DPP xor1 (VALU).
      float sva[8], spv[8];
      #pragma unroll
      for (int s = 0; s < 8; ++s) {
        sva[s] = dppq<DPP_XOR1>(va[s]);
        spv[s] = dppq<DPP_XOR1>(pvb[s]);
      }
      if (!(lane & 1)) {
        if (t >= tprod) {                       // row fa = va lower + pvb upper
          float* o = out + (size_t)fa * 256 + base;
          ((float4*)o)[0] = make_float4(va[0]+spv[0], va[1]+spv[1], va[2]+spv[2], va[3]+spv[3]);
          ((float4*)o)[1] = make_float4(va[4]+spv[4], va[5]+spv[5], va[6]+spv[6], va[7]+spv[7]);
        }
        if (fb <= tprod + 7) {                  // row fb = vb lower + va upper
          float* o = out + (size_t)fb * 256 + base;
          ((float4*)o)[0] = make_float4(vb[0]+sva[0], vb[1]+sva[1], vb[2]+sva[2], vb[3]+sva[3]);
          ((float4*)o)[1] = make_float4(vb[4]+sva[4], vb[5]+sva[5], vb[6]+sva[6], vb[7]+sva[7]);
        }
      }
      #pragma unroll
      for (int s = 0; s < 8; ++s) pvb[s] = vb[s];
    }
  }
#undef LOADTF
#undef LOADNOISE
#undef STEP
}

extern "C" void kernel_launch(void* const* d_in, const int* in_sizes, int n_in,
                              void* d_out, int out_size, void* d_ws, size_t ws_size,
                              hipStream_t stream) {
  (void)in_sizes; (void)n_in; (void)ws_size; (void)out_size; (void)d_ws;
  const float* noise = (const float*)d_in[1];
  const float* env   = (const float*)d_in[2];
  const float* tfr   = (const float*)d_in[3];
  const float* tfi   = (const float*)d_in[4];
  float* out = (float*)d_out;
  // Single fused kernel; no workspace needed (every out row fully written).
  ks_mega<<<dim3(NCHUNK / 4), dim3(256), 0, stream>>>(noise, env, tfr, tfi, out);
}

// Round 6
// 218.322 us; speedup vs baseline: 2.2974x; 1.1399x over previous
//
#include <hip/hip_runtime.h>
#include <math.h>

// ---------------------------------------------------------------------------
// KarplusStrong, fully fused single kernel.
//   C_t = Wconv3( tf_t ⊙ (C_{t-1} + P_t) ),  P_t = rfft(imps_t)  (spectral
//   recurrence, 3-tap hamming conv, Im=0 at bins 0,256). Contraction =>
//   6-step warmup per 8-frame chunk.
//
// R14: pipelined coverage at R10 register pressure.
//  - R13 post-mortem: coverage helped ~15% per-wave but VGPR=132 crossed the
//    128 boundary (3 waves/SIMD) and the always-computed last FFT added 13%
//    waste -> net regression 107->138us.
//  - Fix 1: merge+P-write moved from loop-top (iter t+2) to right after
//    fft_tail (iter t). z dies where izr/izi are born -> peak pressure back
//    to ~R10 (116). Requires separate Pld/LcS buffers again (P(t+2) write
//    must not clobber Lc(t) before the invFFT reads it): LDS 37.4KB,
//    4 blocks/CU — same cap as VGPR, no occupancy loss.
//  - Fix 2: steps 2/3/6 guarded by (t+2 < tend): no wasted last FFT.
//  - Fix 3: P-reads issued BEFORE fft_head (data ready since last iter);
//    head covers the ~150cy LDS read latency.
//  Coverage map: Pw(t+2)->Pr(t+2) spans a full iteration; LcW->LcR covered
//  by noise-prefetch + fft_tail + merge; Pr->use covered by head.
// ---------------------------------------------------------------------------

#define N_ITER   32768
#define NBINS    257
#define BLOCK_N  512
#define FCH      8
#define NCHUNK   (N_ITER / FCH)     // 4096 waves
#define OUT_LEN  8388608

__device__ __forceinline__ int brev6(int x) { return (int)(__brev((unsigned)x) >> 26); }
__device__ __forceinline__ int PDK(int k) { return k + (k >> 3); }
#define PLDSZ 289

// DPP exchange (VALU, not LDS pipe). CTRL=0xB1: lane^1 (quad_perm);
// 0x4E: lane^2 (quad_perm); 0x128: row_ror:8 == lane^8 within 16-lane rows.
template<int CTRL>
__device__ __forceinline__ float dppq(float x) {
  union { float f; int i; } u; u.f = x;
  u.i = __builtin_amdgcn_update_dpp(u.i, u.i, CTRL, 0xF, 0xF, false);
  return u.f;
}
#define DPP_XOR1 0xB1
#define DPP_XOR2 0x4E
#define DPP_XOR8 0x128

// gfx950 VALU half-wave swaps: partner value z[lane^32] / z[lane^16].
// v_permlane32_swap_b32 returns r[0]=new-vdst={x_lo,x_lo},
// r[1]=new-vsrc={x_hi,x_hi}; partner: lo lanes take r[1], hi take r[0].
__device__ __forceinline__ float pswap32(float x, int lane) {
#if __has_builtin(__builtin_amdgcn_permlane32_swap)
  typedef unsigned v2u __attribute__((ext_vector_type(2)));
  union { float f; unsigned u; } v; v.f = x;
  v2u r = __builtin_amdgcn_permlane32_swap(v.u, v.u, false, false);
  union { unsigned u; float f; } o; o.u = (lane & 32) ? r[0] : r[1];
  return o.f;
#else
  return __shfl_xor(x, 32, 64);
#endif
}
// v_permlane16_swap_b32: r[0] rows={x0,x0,x2,x2}, r[1] rows={x1,x1,x3,x3}.
// Partner x[lane^16]: rows 0,2 take r[1]; rows 1,3 take r[0].
__device__ __forceinline__ float pswap16(float x, int lane) {
#if __has_builtin(__builtin_amdgcn_permlane16_swap)
  typedef unsigned v2u __attribute__((ext_vector_type(2)));
  union { float f; unsigned u; } v; v.f = x;
  v2u r = __builtin_amdgcn_permlane16_swap(v.u, v.u, false, false);
  union { unsigned u; float f; } o; o.u = (lane & 16) ? r[0] : r[1];
  return o.f;
#else
  return __shfl_xor(x, 16, 64);
#endif
}

// 512-pt complex DIF FFT across one wave: reg c, lane l <-> position 64c+l.
// Natural-order input; output at position i holds X[brev9(i)].
// TS=+1: forward (e^-i); TS=-1: inverse kernel (e^+i), unnormalized.
// Split into head (reg stages + m=32/16/8, VALU-only) and tail (m=4 DS,
// m=2/1 DPP) so the caller can interleave LDS round-trips between them.

#define LANE_STAGE(MBIT, EXCH)                                                 \
  {                                                                            \
    float nwr = wr*wr - wi*wi, nwi = 2.f*wr*wi;                                \
    wr = nwr; wi = nwi;                                                        \
    _Pragma("unroll")                                                          \
    for (int c = 0; c < 8; ++c) {                                              \
      float pr_ = EXCH(zr[c]);                                                 \
      float pi_ = EXCH(zi[c]);                                                 \
      bool hi = (lane & (MBIT)) != 0;                                          \
      float sr_ = zr[c] + pr_, si_ = zi[c] + pi_;                              \
      float dr = zr[c] - pr_, di = zi[c] - pi_;                                \
      float qr = dr*wr - di*wi, qi = dr*wi + di*wr;                            \
      zr[c] = hi ? qr : sr_;                                                   \
      zi[c] = hi ? qi : si_;                                                   \
    }                                                                          \
  }
#define EX32(x) pswap32((x), lane)
#define EX16(x) pswap16((x), lane)
#define EX8(x)  dppq<DPP_XOR8>(x)
#define EX4(x)  __shfl_xor((x), 4, 64)

template<int TS>
__device__ __forceinline__ void fft512_head(float (&zr)[8], float (&zi)[8], int lane,
                                            float &wr, float &wi) {
  const float ts = (float)TS;
  float s1, c1;
  __sincosf((float)lane * (3.14159265358979323846f / 256.0f), &s1, &c1);
  const float v1r = c1, v1i = -ts * s1;            // e^{-i ts pi l/256}
  const float SQ = 0.70710678118654752f;
  {
    const float r4r[4] = {1.f, SQ, 0.f, -SQ};
    const float r4i[4] = {0.f, -ts*SQ, -ts, -ts*SQ};
    #pragma unroll
    for (int c = 0; c < 4; ++c) {
      float twr = v1r*r4r[c] - v1i*r4i[c];
      float twi = v1r*r4i[c] + v1i*r4r[c];
      float ar = zr[c], ai = zi[c], br = zr[c+4], bi = zi[c+4];
      zr[c] = ar + br; zi[c] = ai + bi;
      float dr = ar - br, di = ai - bi;
      zr[c+4] = dr*twr - di*twi; zi[c+4] = dr*twi + di*twr;
    }
  }
  const float v2r = v1r*v1r - v1i*v1i, v2i = 2.f*v1r*v1i;
  #pragma unroll
  for (int c0 = 0; c0 < 8; c0 += 4) {
    #pragma unroll
    for (int cc = 0; cc < 2; ++cc) {
      int c = c0 + cc;
      float ar = zr[c], ai = zi[c], br = zr[c+2], bi = zi[c+2];
      zr[c] = ar + br; zi[c] = ai + bi;
      float dr = ar - br, di = ai - bi;
      float qr = dr*v2r - di*v2i, qi = dr*v2i + di*v2r;
      if (cc) { float t_ = qr; qr = ts*qi; qi = -ts*t_; }
      zr[c+2] = qr; zi[c+2] = qi;
    }
  }
  wr = v2r*v2r - v2i*v2i; wi = 2.f*v2r*v2i;
  #pragma unroll
  for (int c = 0; c < 8; c += 2) {
    float ar = zr[c], ai = zi[c], br = zr[c+1], bi = zi[c+1];
    zr[c] = ar + br; zi[c] = ai + bi;
    float dr = ar - br, di = ai - bi;
    zr[c+1] = dr*wr - di*wi; zi[c+1] = dr*wi + di*wr;
  }
  LANE_STAGE(32, EX32)
  LANE_STAGE(16, EX16)
  LANE_STAGE(8,  EX8)
}

template<int TS>
__device__ __forceinline__ void fft512_tail(float (&zr)[8], float (&zi)[8], int lane,
                                            float &wr, float &wi) {
  LANE_STAGE(4, EX4)
  // ---- stage m=2 via DPP quad_perm (xor2) ----
  {
    float nwr = wr*wr - wi*wi, nwi = 2.f*wr*wi;
    wr = nwr; wi = nwi;
    #pragma unroll
    for (int c = 0; c < 8; ++c) {
      float pr_ = dppq<DPP_XOR2>(zr[c]);
      float pi_ = dppq<DPP_XOR2>(zi[c]);
      bool hi = (lane & 2) != 0;
      float sr_ = zr[c] + pr_, si_ = zi[c] + pi_;
      float dr = zr[c] - pr_, di = zi[c] - pi_;
      float qr = dr*wr - di*wi, qi = dr*wi + di*wr;
      zr[c] = hi ? qr : sr_;
      zi[c] = hi ? qi : si_;
    }
  }
  // ---- stage m=1 via DPP quad_perm (xor1), tw = 1 ----
  #pragma unroll
  for (int c = 0; c < 8; ++c) {
    float pr_ = dppq<DPP_XOR1>(zr[c]);
    float pi_ = dppq<DPP_XOR1>(zi[c]);
    bool hi = (lane & 1) != 0;
    zr[c] = hi ? (pr_ - zr[c]) : (zr[c] + pr_);
    zi[c] = hi ? (pi_ - zi[c]) : (zi[c] + pi_);
  }
}

template<int TS>
__device__ __forceinline__ void fft512_regs(float (&zr)[8], float (&zi)[8], int lane) {
  float wr, wi;
  fft512_head<TS>(zr, zi, lane, wr, wi);
  fft512_tail<TS>(zr, zi, lane, wr, wi);
}

#undef LANE_STAGE
#undef EX32
#undef EX16
#undef EX8
#undef EX4

__global__ __launch_bounds__(256) void ks_mega(const float* __restrict__ noise,
                                               const float* __restrict__ env,
                                               const float* __restrict__ tfr,
                                               const float* __restrict__ tfi,
                                               float* __restrict__ out) {
  // Separate buffers (R14): P(t+2) is written while Lc(t) is still pending
  // its invFFT read, so they may not alias. Per-wave DS order per iter:
  // Pr(t), LcW(t,t+1), PW(t+2), LcR(t) — in-order DS pipe keeps this safe.
  __shared__ float2 Pld[4][2][PLDSZ];
  __shared__ float2 LcS[4][2][PLDSZ];
  const int w = threadIdx.x >> 6, lane = threadIdx.x & 63;
  const int j = blockIdx.x * 4 + w;
  const int k0 = lane * 4;
  const bool l63 = (lane == 63);
  const int rr = brev6(lane);
  const int base = 8 * rr;
  const int tprod = j * FCH;
  const int t0 = (j == 0) ? 0 : (tprod - 6);
  const int tend = tprod + FCH;
  float2* Pw0 = &Pld[w][0][0];
  float2* Pw1 = &Pld[w][1][0];
  float2* Lc0 = &LcS[w][0][0];
  float2* Lc1 = &LcS[w][1][0];
  const float sc = 1.0f / 512.0f;
  const int CB3[8] = {0,4,2,6,1,5,3,7};

  float Cr[4] = {0.f,0.f,0.f,0.f}, Ci[4] = {0.f,0.f,0.f,0.f};
  float C256 = 0.f;
  float tr[2][4], ti[2][4];
  float t6r[2] = {0.f,0.f}, t6i[2] = {0.f,0.f};
  float nA[8], nB[8], eA, eB;
  float pvb[8] = {0.f,0.f,0.f,0.f,0.f,0.f,0.f,0.f};

  // j==0 pre-pair: frame -1 = 0, frame 0 = imps0 (zero spectrum). Emit row 0
  // (= imps0 lower half) and seed pvb with frame 0.
  if (j == 0) {
    const float e0 = env[0]; const float e02 = e0 * e0;
    const float* n0 = noise + base;
    float q[8];
    *(float4*)(&q[0]) = *(const float4*)(n0);
    *(float4*)(&q[4]) = *(const float4*)(n0 + 4);
    #pragma unroll
    for (int s = 0; s < 8; ++s) pvb[s] = (2.f * q[s] - 1.f) * e02;
    if (!(lane & 1)) {
      float* o = out + base;
      ((float4*)o)[0] = make_float4(pvb[0], pvb[1], pvb[2], pvb[3]);
      ((float4*)o)[1] = make_float4(pvb[4], pvb[5], pvb[6], pvb[7]);
    }
  }

#define LOADTF(S, TS_) do {                                                    \
    const size_t _bt = (size_t)(TS_) * NBINS;                                  \
    _Pragma("unroll") for (int _i = 0; _i < 4; ++_i) {                         \
      tr[S][_i] = tfr[_bt + k0 + _i];                                          \
      ti[S][_i] = tfi[_bt + k0 + _i];                                          \
    }                                                                          \
    if (l63) { t6r[S] = tfr[_bt + 256]; t6i[S] = tfi[_bt + 256]; }             \
  } while (0)

#define LOADNOISE(TA, TB) do {                                                 \
    const float* _pa = noise + (size_t)(TA) * BLOCK_N;                         \
    const float* _pb = noise + (size_t)(TB) * BLOCK_N;                         \
    _Pragma("unroll") for (int _c = 0; _c < 8; ++_c) {                         \
      nA[_c] = _pa[64*_c + lane];                                              \
      nB[_c] = _pb[64*_c + lane];                                              \
    }                                                                          \
    eA = env[TA]; eB = env[TB];                                                \
  } while (0)

// Hermitian merge of packed fwd-FFT result z -> P spectra, written to Pld.
#define MERGEP() do {                                                          \
    float mr[8], mi[8];                                                        \
    {                                                                          \
      int lam = brev6((64 - rr) & 63);                                         \
      mr[0] = __shfl(zr[0], lam, 64); mi[0] = __shfl(zi[0], lam, 64);          \
    }                                                                          \
    mr[1] = __shfl_xor(zr[1], 63, 64); mi[1] = __shfl_xor(zi[1], 63, 64);      \
    mr[2] = __shfl_xor(zr[3], 63, 64); mi[2] = __shfl_xor(zi[3], 63, 64);      \
    mr[3] = __shfl_xor(zr[2], 63, 64); mi[3] = __shfl_xor(zi[2], 63, 64);      \
    mr[4] = __shfl_xor(zr[7], 63, 64); mi[4] = __shfl_xor(zi[7], 63, 64);      \
    mr[5] = __shfl_xor(zr[6], 63, 64); mi[5] = __shfl_xor(zi[6], 63, 64);      \
    mr[6] = __shfl_xor(zr[5], 63, 64); mi[6] = __shfl_xor(zi[5], 63, 64);      \
    mr[7] = __shfl_xor(zr[4], 63, 64); mi[7] = __shfl_xor(zi[4], 63, 64);      \
    if (!(lane & 1)) {                                                         \
      _Pragma("unroll") for (int s = 0; s < 8; ++s) {                          \
        int c = CB3[s];                                                        \
        int k = 8 * rr + s;                                                    \
        Pw0[PDK(k)] = make_float2(0.5f*(zr[c] + mr[c]), 0.5f*(zi[c] - mi[c])); \
        Pw1[PDK(k)] = make_float2(0.5f*(zi[c] + mi[c]), 0.5f*(mr[c] - zr[c])); \
      }                                                                        \
    } else if (lane == 1) {                                                    \
      Pw0[PDK(256)] = make_float2(0.5f*(zr[0] + mr[0]), 0.5f*(zi[0] - mi[0])); \
      Pw1[PDK(256)] = make_float2(0.5f*(zi[0] + mi[0]), 0.5f*(mr[0] - zr[0])); \
    }                                                                          \
  } while (0)

// One recurrence step; stash C_t to LDS (recur layout) when it will feed an
// inverse FFT (t >= tprod-2).
#define STEP(S, T, PR, PI, P6R, P6I) do {                                      \
    const int _t = (T);                                                        \
    float Vr[4], Vi[4];                                                        \
    _Pragma("unroll") for (int _i = 0; _i < 4; ++_i) {                         \
      float Ur = Cr[_i] + PR[_i], Ui = Ci[_i] + PI[_i];                        \
      Vr[_i] = tr[S][_i]*Ur - ti[S][_i]*Ui;                                    \
      Vi[_i] = tr[S][_i]*Ui + ti[S][_i]*Ur;                                    \
    }                                                                          \
    if (lane == 0) Vi[0] = 0.f;                                                \
    float U6r = C256 + P6R, U6i = P6I;                                         \
    float V6r = t6r[S]*U6r - t6i[S]*U6i;                                       \
    int _tf = _t + 2; if (_tf > N_ITER - 1) _tf = N_ITER - 1;                  \
    LOADTF(S, _tf);                                                            \
    float Lr = __shfl_up(Vr[3], 1),   Li = __shfl_up(Vi[3], 1);                \
    float Rr = __shfl_down(Vr[0], 1), Ri = __shfl_down(Vi[0], 1);              \
    if (lane == 0) { Lr = Vr[1]; Li = -Vi[1]; }                                \
    if (l63)       { Rr = V6r;   Ri = 0.f; }                                   \
    Cr[0] = 0.54f*Vr[0] - 0.23f*(Lr    + Vr[1]);                               \
    Ci[0] = 0.54f*Vi[0] - 0.23f*(Li    + Vi[1]);                               \
    Cr[1] = 0.54f*Vr[1] - 0.23f*(Vr[0] + Vr[2]);                               \
    Ci[1] = 0.54f*Vi[1] - 0.23f*(Vi[0] + Vi[2]);                               \
    Cr[2] = 0.54f*Vr[2] - 0.23f*(Vr[1] + Vr[3]);                               \
    Ci[2] = 0.54f*Vi[2] - 0.23f*(Vi[1] + Vi[3]);                               \
    Cr[3] = 0.54f*Vr[3] - 0.23f*(Vr[2] + Rr);                                  \
    Ci[3] = 0.54f*Vi[3] - 0.23f*(Vi[2] + Ri);                                  \
    C256  = 0.54f*V6r   - 0.46f*Vr[3];                                         \
    if (_t >= tprod - 2) {                                                     \
      float2* _Ls = ((_t) & 1) ? Lc1 : Lc0;                                    \
      _Ls[PDK(k0 + 0)] = make_float2(Cr[0], Ci[0]);                            \
      _Ls[PDK(k0 + 1)] = make_float2(Cr[1], Ci[1]);                            \
      _Ls[PDK(k0 + 2)] = make_float2(Cr[2], Ci[2]);                            \
      _Ls[PDK(k0 + 3)] = make_float2(Cr[3], Ci[3]);                            \
      if (l63) _Ls[PDK(256)] = make_float2(C256, 0.f);                         \
    }                                                                          \
  } while (0)

  LOADTF(0, t0);
  LOADTF(1, t0 + 1);

  // Prologue: P(t0) <- fft(imps(t0,t0+1)); prefetch noise for pair t0+2.
  float zr[8], zi[8];
  {
    const float* p0 = noise + (size_t)t0 * BLOCK_N;
    const float* p1 = noise + (size_t)(t0 + 1) * BLOCK_N;
    const float e0 = env[t0], e1 = env[t0 + 1];
    const float e02 = e0 * e0, e12 = e1 * e1;
    #pragma unroll
    for (int c = 0; c < 8; ++c) {
      zr[c] = (2.f * p0[64*c + lane] - 1.f) * e02;
      zi[c] = (2.f * p1[64*c + lane] - 1.f) * e12;
    }
    fft512_regs<1>(zr, zi, lane);
    MERGEP();
  }
  LOADNOISE(t0 + 2, t0 + 3);

  for (int t = t0; t < tend; t += 2) {
    const bool notlast = (t + 2 < tend);
    // ---- 2. imps(t+2, t+3) from prefetched noise (overwrites z) ----
    if (notlast) {
      const float ea2 = eA * eA, eb2 = eB * eB;
      #pragma unroll
      for (int c = 0; c < 8; ++c) {
        zr[c] = (2.f * nA[c] - 1.f) * ea2;
        zi[c] = (2.f * nB[c] - 1.f) * eb2;
      }
    }
    // ---- 4a. issue P(t) reads (data ready since last iter; latency
    //          covered by the FFT head below) ----
    float pr0[4], pi0[4], pr1[4], pi1[4];
    float p60r = 0.f, p60i = 0.f, p61r = 0.f, p61i = 0.f;
    #pragma unroll
    for (int i = 0; i < 4; ++i) {
      float2 q0 = Pw0[PDK(k0 + i)];
      float2 q1 = Pw1[PDK(k0 + i)];
      pr0[i] = q0.x; pi0[i] = q0.y;
      pr1[i] = q1.x; pi1[i] = q1.y;
    }
    if (l63) {
      float2 q0 = Pw0[PDK(256)]; p60r = q0.x; p60i = q0.y;
      float2 q1 = Pw1[PDK(256)]; p61r = q1.x; p61i = q1.y;
    }
    // ---- 3. fwd FFT HEAD (VALU-only): covers the P-read latency ----
    float wr_, wi_;
    if (notlast) fft512_head<1>(zr, zi, lane, wr_, wi_);
    // ---- 5. two recurrence steps (stash C to Lc when inv-active) ----
    STEP(0, t,     pr0, pi0, p60r, p60i);
    STEP(1, t + 1, pr1, pi1, p61r, p61i);
    // ---- 5.5 noise prefetch for pair t+4 (consumed next iter) ----
    if (t + 4 < tend) LOADNOISE(t + 4, t + 5);
    // ---- 6. fwd FFT TAIL + merge + P(t+2) write: covers Lc wr->rd ----
    if (notlast) {
      fft512_tail<1>(zr, zi, lane, wr_, wi_);
      MERGEP();
    }
    // ---- 7-10. packed inverse FFT of (C[t], C[t+1]) -> frames (t+1,t+2) ----
    if (t >= tprod - 2) {
      float izr[8], izi[8];
      #pragma unroll
      for (int c = 0; c < 8; ++c) {
        int k = 64 * c + lane;
        bool mir = (k > 256);
        int idx = mir ? (512 - k) : k;
        float2 a = Lc0[PDK(idx)];
        float2 b = Lc1[PDK(idx)];
        float ay = mir ? -a.y : a.y;
        float by = mir ?  b.y : -b.y;
        izr[c] = sc * (a.x + by);
        izi[c] = sc * (b.x + ay);
      }
      fft512_regs<-1>(izr, izi, lane);
      const int fa = t + 1;
      int fb = t + 2; int nfb = (fb > N_ITER - 1) ? (N_ITER - 1) : fb;
      const float efa = env[fa];  const float efa2 = efa * efa;
      const float efb = env[nfb]; const float efb2 = efb * efb;
      const float* na_ = noise + (size_t)fa  * BLOCK_N + base;
      const float* nb_ = noise + (size_t)nfb * BLOCK_N + base;
      float Aa[8], Bb[8];
      *(float4*)(&Aa[0]) = *(const float4*)(na_);
      *(float4*)(&Aa[4]) = *(const float4*)(na_ + 4);
      *(float4*)(&Bb[0]) = *(const float4*)(nb_);
      *(float4*)(&Bb[4]) = *(const float4*)(nb_ + 4);
      float va[8], vb[8];
      #pragma unroll
      for (int s = 0; s < 8; ++s) {
        int c = CB3[s];
        va[s] = izr[c] + (2.f * Aa[s] - 1.f) * efa2;
        vb[s] = izi[c] + (2.f * Bb[s] - 1.f) * efb2;
      }
      // Half-merge exchanges via DPP xor1 (VALU).
      float sva[8], spv[8];
      #pragma unroll
      for (int s = 0; s < 8; ++s) {
        sva[s] = dppq<DPP_XOR1>(va[s]);
        spv[s] = dppq<DPP_XOR1>(pvb[s]);
      }
      if (!(lane & 1)) {
        if (t >= tprod) {                       // row fa = va lower + pvb upper
          float* o = out + (size_t)fa * 256 + base;
          ((float4*)o)[0] = make_float4(va[0]+spv[0], va[1]+spv[1], va[2]+spv[2], va[3]+spv[3]);
          ((float4*)o)[1] = make_float4(va[4]+spv[4], va[5]+spv[5], va[6]+spv[6], va[7]+spv[7]);
        }
        if (fb <= tprod + 7) {                  // row fb = vb lower + va upper
          float* o = out + (size_t)fb * 256 + base;
          ((float4*)o)[0] = make_float4(vb[0]+sva[0], vb[1]+sva[1], vb[2]+sva[2], vb[3]+sva[3]);
          ((float4*)o)[1] = make_float4(vb[4]+sva[4], vb[5]+sva[5], vb[6]+sva[6], vb[7]+sva[7]);
        }
      }
      #pragma unroll
      for (int s = 0; s < 8; ++s) pvb[s] = vb[s];
    }
  }
#undef LOADTF
#undef LOADNOISE
#undef MERGEP
#undef STEP
}

extern "C" void kernel_launch(void* const* d_in, const int* in_sizes, int n_in,
                              void* d_out, int out_size, void* d_ws, size_t ws_size,
                              hipStream_t stream) {
  (void)in_sizes; (void)n_in; (void)ws_size; (void)out_size; (void)d_ws;
  const float* noise = (const float*)d_in[1];
  const float* env   = (const float*)d_in[2];
  const float* tfr   = (const float*)d_in[3];
  const float* tfi   = (const float*)d_in[4];
  float* out = (float*)d_out;
  // Single fused kernel; no workspace needed (every out row fully written).
  ks_mega<<<dim3(NCHUNK / 4), dim3(256), 0, stream>>>(noise, env, tfr, tfi, out);
}

// Round 7
// 210.676 us; speedup vs baseline: 2.3807x; 1.0363x over previous
//
#include <hip/hip_runtime.h>
#include <math.h>

// ---------------------------------------------------------------------------
// KarplusStrong, fully fused single kernel (R10-verified structure).
//   C_t = Wconv3( tf_t ⊙ (C_{t-1} + P_t) ),  P_t = rfft(imps_t)  (spectral
//   recurrence, 3-tap hamming conv, Im=0 at bins 0,256). Contraction =>
//   warmup per 8-frame chunk.
//
// R15: R10 verbatim with warmup 6 -> 4 (t0 = tprod-4).
//  - R13/R14 post-mortems: every reordering of R10's schedule (sw-pipelined
//    fwd FFT, early P-reads, late merge) ADDED stall (107 -> 138/148us).
//    R10's write-then-read schedule + compiler waitcnt placement is already
//    near-optimal for this structure. Scheduling micro-surgery abandoned.
//  - Instead reduce steps: recurrence is a contraction with factor
//    max|tf|*||Wconv|| <= 0.2*sqrt(2)*1 ~= 0.283. Warmup-4 truncation error
//    ~0.283^4 ~= 6.4e-3 absolute vs threshold 4.09e-2 (current absmax
//    7.8e-3, slack 5x). Steps/wave 14 -> 12 (-14.3%).
// ---------------------------------------------------------------------------

#define N_ITER   32768
#define NBINS    257
#define BLOCK_N  512
#define FCH      8
#define NCHUNK   (N_ITER / FCH)     // 4096 waves
#define OUT_LEN  8388608

__device__ __forceinline__ int brev6(int x) { return (int)(__brev((unsigned)x) >> 26); }
__device__ __forceinline__ int PDK(int k) { return k + (k >> 3); }
#define PLDSZ 289

// DPP exchange (VALU, not LDS pipe). CTRL=0xB1: lane^1 (quad_perm);
// 0x4E: lane^2 (quad_perm); 0x128: row_ror:8 == lane^8 within 16-lane rows.
template<int CTRL>
__device__ __forceinline__ float dppq(float x) {
  union { float f; int i; } u; u.f = x;
  u.i = __builtin_amdgcn_update_dpp(u.i, u.i, CTRL, 0xF, 0xF, false);
  return u.f;
}
#define DPP_XOR1 0xB1
#define DPP_XOR2 0x4E
#define DPP_XOR8 0x128

// gfx950 VALU half-wave swaps: partner value z[lane^32] / z[lane^16].
// v_permlane32_swap_b32 returns r[0]=new-vdst={x_lo,x_lo},
// r[1]=new-vsrc={x_hi,x_hi}; partner: lo lanes take r[1], hi take r[0].
__device__ __forceinline__ float pswap32(float x, int lane) {
#if __has_builtin(__builtin_amdgcn_permlane32_swap)
  typedef unsigned v2u __attribute__((ext_vector_type(2)));
  union { float f; unsigned u; } v; v.f = x;
  v2u r = __builtin_amdgcn_permlane32_swap(v.u, v.u, false, false);
  union { unsigned u; float f; } o; o.u = (lane & 32) ? r[0] : r[1];
  return o.f;
#else
  return __shfl_xor(x, 32, 64);
#endif
}
// v_permlane16_swap_b32: r[0] rows={x0,x0,x2,x2}, r[1] rows={x1,x1,x3,x3}.
// Partner x[lane^16]: rows 0,2 take r[1]; rows 1,3 take r[0].
__device__ __forceinline__ float pswap16(float x, int lane) {
#if __has_builtin(__builtin_amdgcn_permlane16_swap)
  typedef unsigned v2u __attribute__((ext_vector_type(2)));
  union { float f; unsigned u; } v; v.f = x;
  v2u r = __builtin_amdgcn_permlane16_swap(v.u, v.u, false, false);
  union { unsigned u; float f; } o; o.u = (lane & 16) ? r[0] : r[1];
  return o.f;
#else
  return __shfl_xor(x, 16, 64);
#endif
}

// 512-pt complex DIF FFT across one wave: reg c, lane l <-> position 64c+l.
// Natural-order input; output at position i holds X[brev9(i)].
// TS=+1: forward (e^-i); TS=-1: inverse kernel (e^+i), unnormalized.
template<int TS>
__device__ __forceinline__ void fft512_regs(float (&zr)[8], float (&zi)[8], int lane) {
  const float ts = (float)TS;
  float s1, c1;
  __sincosf((float)lane * (3.14159265358979323846f / 256.0f), &s1, &c1);
  const float v1r = c1, v1i = -ts * s1;            // e^{-i ts pi l/256}
  const float SQ = 0.70710678118654752f;
  {
    const float r4r[4] = {1.f, SQ, 0.f, -SQ};
    const float r4i[4] = {0.f, -ts*SQ, -ts, -ts*SQ};
    #pragma unroll
    for (int c = 0; c < 4; ++c) {
      float twr = v1r*r4r[c] - v1i*r4i[c];
      float twi = v1r*r4i[c] + v1i*r4r[c];
      float ar = zr[c], ai = zi[c], br = zr[c+4], bi = zi[c+4];
      zr[c] = ar + br; zi[c] = ai + bi;
      float dr = ar - br, di = ai - bi;
      zr[c+4] = dr*twr - di*twi; zi[c+4] = dr*twi + di*twr;
    }
  }
  const float v2r = v1r*v1r - v1i*v1i, v2i = 2.f*v1r*v1i;
  #pragma unroll
  for (int c0 = 0; c0 < 8; c0 += 4) {
    #pragma unroll
    for (int cc = 0; cc < 2; ++cc) {
      int c = c0 + cc;
      float ar = zr[c], ai = zi[c], br = zr[c+2], bi = zi[c+2];
      zr[c] = ar + br; zi[c] = ai + bi;
      float dr = ar - br, di = ai - bi;
      float qr = dr*v2r - di*v2i, qi = dr*v2i + di*v2r;
      if (cc) { float t_ = qr; qr = ts*qi; qi = -ts*t_; }
      zr[c+2] = qr; zi[c+2] = qi;
    }
  }
  float wr = v2r*v2r - v2i*v2i, wi = 2.f*v2r*v2i;
  #pragma unroll
  for (int c = 0; c < 8; c += 2) {
    float ar = zr[c], ai = zi[c], br = zr[c+1], bi = zi[c+1];
    zr[c] = ar + br; zi[c] = ai + bi;
    float dr = ar - br, di = ai - bi;
    zr[c+1] = dr*wr - di*wi; zi[c+1] = dr*wi + di*wr;
  }
  // lane stages m=32..4: chain w; twiddle is -w on hi lanes, so
  // out_hi = (x_hi - x_lo)*w.  m=32/16 via permlane*_swap (VALU),
  // m=8 via DPP row_ror:8 (VALU), m=4 via shuffle (DS pipe).
#define LANE_STAGE(MBIT, EXCH)                                                 \
  {                                                                            \
    float nwr = wr*wr - wi*wi, nwi = 2.f*wr*wi;                                \
    wr = nwr; wi = nwi;                                                        \
    _Pragma("unroll")                                                          \
    for (int c = 0; c < 8; ++c) {                                              \
      float pr_ = EXCH(zr[c]);                                                 \
      float pi_ = EXCH(zi[c]);                                                 \
      bool hi = (lane & (MBIT)) != 0;                                          \
      float sr_ = zr[c] + pr_, si_ = zi[c] + pi_;                              \
      float dr = zr[c] - pr_, di = zi[c] - pi_;                                \
      float qr = dr*wr - di*wi, qi = dr*wi + di*wr;                            \
      zr[c] = hi ? qr : sr_;                                                   \
      zi[c] = hi ? qi : si_;                                                   \
    }                                                                          \
  }
#define EX32(x) pswap32((x), lane)
#define EX16(x) pswap16((x), lane)
#define EX8(x)  dppq<DPP_XOR8>(x)
#define EX4(x)  __shfl_xor((x), 4, 64)
  LANE_STAGE(32, EX32)
  LANE_STAGE(16, EX16)
  LANE_STAGE(8,  EX8)
  LANE_STAGE(4,  EX4)
#undef LANE_STAGE
#undef EX32
#undef EX16
#undef EX8
#undef EX4
  // ---- stage m=2 via DPP quad_perm (xor2) ----
  {
    float nwr = wr*wr - wi*wi, nwi = 2.f*wr*wi;
    wr = nwr; wi = nwi;
    #pragma unroll
    for (int c = 0; c < 8; ++c) {
      float pr_ = dppq<DPP_XOR2>(zr[c]);
      float pi_ = dppq<DPP_XOR2>(zi[c]);
      bool hi = (lane & 2) != 0;
      float sr_ = zr[c] + pr_, si_ = zi[c] + pi_;
      float dr = zr[c] - pr_, di = zi[c] - pi_;
      float qr = dr*wr - di*wi, qi = dr*wi + di*wr;
      zr[c] = hi ? qr : sr_;
      zi[c] = hi ? qi : si_;
    }
  }
  // ---- stage m=1 via DPP quad_perm (xor1), tw = 1 ----
  #pragma unroll
  for (int c = 0; c < 8; ++c) {
    float pr_ = dppq<DPP_XOR1>(zr[c]);
    float pi_ = dppq<DPP_XOR1>(zi[c]);
    bool hi = (lane & 1) != 0;
    zr[c] = hi ? (pr_ - zr[c]) : (zr[c] + pr_);
    zi[c] = hi ? (pi_ - zi[c]) : (zi[c] + pi_);
  }
}

__global__ __launch_bounds__(256) void ks_mega(const float* __restrict__ noise,
                                               const float* __restrict__ env,
                                               const float* __restrict__ tfr,
                                               const float* __restrict__ tfi,
                                               float* __restrict__ out) {
  __shared__ float2 Pld[4][2][PLDSZ];
  __shared__ float2 LcS[4][2][PLDSZ];
  const int w = threadIdx.x >> 6, lane = threadIdx.x & 63;
  const int j = blockIdx.x * 4 + w;
  const int k0 = lane * 4;
  const bool l63 = (lane == 63);
  const int rr = brev6(lane);
  const int base = 8 * rr;
  const int tprod = j * FCH;
  const int t0 = (j == 0) ? 0 : (tprod - 4);   // R15: warmup 6 -> 4
  const int tend = tprod + FCH;
  float2* Pw0 = &Pld[w][0][0];
  float2* Pw1 = &Pld[w][1][0];
  float2* Lc0 = &LcS[w][0][0];
  float2* Lc1 = &LcS[w][1][0];
  const float sc = 1.0f / 512.0f;
  const int CB3[8] = {0,4,2,6,1,5,3,7};

  float Cr[4] = {0.f,0.f,0.f,0.f}, Ci[4] = {0.f,0.f,0.f,0.f};
  float C256 = 0.f;
  float tr[2][4], ti[2][4];
  float t6r[2] = {0.f,0.f}, t6i[2] = {0.f,0.f};
  float nA[8], nB[8], eA, eB;
  float pvb[8] = {0.f,0.f,0.f,0.f,0.f,0.f,0.f,0.f};

  // j==0 pre-pair: frame -1 = 0, frame 0 = imps0 (zero spectrum). Emit row 0
  // (= imps0 lower half) and seed pvb with frame 0.
  if (j == 0) {
    const float e0 = env[0]; const float e02 = e0 * e0;
    const float* n0 = noise + base;
    float q[8];
    *(float4*)(&q[0]) = *(const float4*)(n0);
    *(float4*)(&q[4]) = *(const float4*)(n0 + 4);
    #pragma unroll
    for (int s = 0; s < 8; ++s) pvb[s] = (2.f * q[s] - 1.f) * e02;
    if (!(lane & 1)) {
      float* o = out + base;
      ((float4*)o)[0] = make_float4(pvb[0], pvb[1], pvb[2], pvb[3]);
      ((float4*)o)[1] = make_float4(pvb[4], pvb[5], pvb[6], pvb[7]);
    }
  }

#define LOADTF(S, TS_) do {                                                    \
    const size_t _bt = (size_t)(TS_) * NBINS;                                  \
    _Pragma("unroll") for (int _i = 0; _i < 4; ++_i) {                         \
      tr[S][_i] = tfr[_bt + k0 + _i];                                          \
      ti[S][_i] = tfi[_bt + k0 + _i];                                          \
    }                                                                          \
    if (l63) { t6r[S] = tfr[_bt + 256]; t6i[S] = tfi[_bt + 256]; }             \
  } while (0)

#define LOADNOISE(TA, TB) do {                                                 \
    const float* _pa = noise + (size_t)(TA) * BLOCK_N;                         \
    const float* _pb = noise + (size_t)(TB) * BLOCK_N;                         \
    _Pragma("unroll") for (int _c = 0; _c < 8; ++_c) {                         \
      nA[_c] = _pa[64*_c + lane];                                              \
      nB[_c] = _pb[64*_c + lane];                                              \
    }                                                                          \
    eA = env[TA]; eB = env[TB];                                                \
  } while (0)

// One recurrence step; stash C_t to LDS (recur layout) when it will feed an
// inverse FFT (t >= tprod-2).
#define STEP(S, T, PR, PI, P6R, P6I) do {                                      \
    const int _t = (T);                                                        \
    float Vr[4], Vi[4];                                                        \
    _Pragma("unroll") for (int _i = 0; _i < 4; ++_i) {                         \
      float Ur = Cr[_i] + PR[_i], Ui = Ci[_i] + PI[_i];                        \
      Vr[_i] = tr[S][_i]*Ur - ti[S][_i]*Ui;                                    \
      Vi[_i] = tr[S][_i]*Ui + ti[S][_i]*Ur;                                    \
    }                                                                          \
    if (lane == 0) Vi[0] = 0.f;                                                \
    float U6r = C256 + P6R, U6i = P6I;                                         \
    float V6r = t6r[S]*U6r - t6i[S]*U6i;                                       \
    int _tf = _t + 2; if (_tf > N_ITER - 1) _tf = N_ITER - 1;                  \
    LOADTF(S, _tf);                                                            \
    float Lr = __shfl_up(Vr[3], 1),   Li = __shfl_up(Vi[3], 1);                \
    float Rr = __shfl_down(Vr[0], 1), Ri = __shfl_down(Vi[0], 1);              \
    if (lane == 0) { Lr = Vr[1]; Li = -Vi[1]; }                                \
    if (l63)       { Rr = V6r;   Ri = 0.f; }                                   \
    Cr[0] = 0.54f*Vr[0] - 0.23f*(Lr    + Vr[1]);                               \
    Ci[0] = 0.54f*Vi[0] - 0.23f*(Li    + Vi[1]);                               \
    Cr[1] = 0.54f*Vr[1] - 0.23f*(Vr[0] + Vr[2]);                               \
    Ci[1] = 0.54f*Vi[1] - 0.23f*(Vi[0] + Vi[2]);                               \
    Cr[2] = 0.54f*Vr[2] - 0.23f*(Vr[1] + Vr[3]);                               \
    Ci[2] = 0.54f*Vi[2] - 0.23f*(Vi[1] + Vi[3]);                               \
    Cr[3] = 0.54f*Vr[3] - 0.23f*(Vr[2] + Rr);                                  \
    Ci[3] = 0.54f*Vi[3] - 0.23f*(Vi[2] + Ri);                                  \
    C256  = 0.54f*V6r   - 0.46f*Vr[3];                                         \
    if (_t >= tprod - 2) {                                                     \
      float2* _Ls = ((_t) & 1) ? Lc1 : Lc0;                                    \
      _Ls[PDK(k0 + 0)] = make_float2(Cr[0], Ci[0]);                            \
      _Ls[PDK(k0 + 1)] = make_float2(Cr[1], Ci[1]);                            \
      _Ls[PDK(k0 + 2)] = make_float2(Cr[2], Ci[2]);                            \
      _Ls[PDK(k0 + 3)] = make_float2(Cr[3], Ci[3]);                            \
      if (l63) _Ls[PDK(256)] = make_float2(C256, 0.f);                         \
    }                                                                          \
  } while (0)

  LOADTF(0, t0);
  LOADTF(1, t0 + 1);
  LOADNOISE(t0, t0 + 1);

  for (int t = t0; t < tend; t += 2) {
    // ---- packed forward FFT of impulses (t, t+1) ----
    const float ea2 = eA * eA, eb2 = eB * eB;
    float zr[8], zi[8];
    #pragma unroll
    for (int c = 0; c < 8; ++c) {
      zr[c] = (2.f * nA[c] - 1.f) * ea2;
      zi[c] = (2.f * nB[c] - 1.f) * eb2;
    }
    {
      int ta = t + 2; if (ta > N_ITER - 1) ta = N_ITER - 1;
      int tb = t + 3; if (tb > N_ITER - 1) tb = N_ITER - 1;
      LOADNOISE(ta, tb);
    }
    fft512_regs<1>(zr, zi, lane);
    float mr[8], mi[8];
    {
      int r_ = brev6(lane);
      int lam = brev6((64 - r_) & 63);
      mr[0] = __shfl(zr[0], lam, 64); mi[0] = __shfl(zi[0], lam, 64);
    }
    mr[1] = __shfl_xor(zr[1], 63, 64); mi[1] = __shfl_xor(zi[1], 63, 64);
    mr[2] = __shfl_xor(zr[3], 63, 64); mi[2] = __shfl_xor(zi[3], 63, 64);
    mr[3] = __shfl_xor(zr[2], 63, 64); mi[3] = __shfl_xor(zi[2], 63, 64);
    mr[4] = __shfl_xor(zr[7], 63, 64); mi[4] = __shfl_xor(zi[7], 63, 64);
    mr[5] = __shfl_xor(zr[6], 63, 64); mi[5] = __shfl_xor(zi[6], 63, 64);
    mr[6] = __shfl_xor(zr[5], 63, 64); mi[6] = __shfl_xor(zi[5], 63, 64);
    mr[7] = __shfl_xor(zr[4], 63, 64); mi[7] = __shfl_xor(zi[4], 63, 64);
    if (!(lane & 1)) {
      #pragma unroll
      for (int s = 0; s < 8; ++s) {
        int c = CB3[s];
        int k = 8 * rr + s;
        Pw0[PDK(k)] = make_float2(0.5f*(zr[c] + mr[c]), 0.5f*(zi[c] - mi[c]));
        Pw1[PDK(k)] = make_float2(0.5f*(zi[c] + mi[c]), 0.5f*(mr[c] - zr[c]));
      }
    } else if (lane == 1) {
      Pw0[PDK(256)] = make_float2(0.5f*(zr[0] + mr[0]), 0.5f*(zi[0] - mi[0]));
      Pw1[PDK(256)] = make_float2(0.5f*(zi[0] + mi[0]), 0.5f*(mr[0] - zr[0]));
    }
    float pr0[4], pi0[4], pr1[4], pi1[4];
    float p60r = 0.f, p60i = 0.f, p61r = 0.f, p61i = 0.f;
    #pragma unroll
    for (int i = 0; i < 4; ++i) {
      float2 q0 = Pw0[PDK(k0 + i)];
      float2 q1 = Pw1[PDK(k0 + i)];
      pr0[i] = q0.x; pi0[i] = q0.y;
      pr1[i] = q1.x; pi1[i] = q1.y;
    }
    if (l63) {
      float2 q0 = Pw0[PDK(256)]; p60r = q0.x; p60i = q0.y;
      float2 q1 = Pw1[PDK(256)]; p61r = q1.x; p61i = q1.y;
    }
    // ---- two recurrence steps (stash C to LDS when inv-active) ----
    STEP(0, t,     pr0, pi0, p60r, p60i);
    STEP(1, t + 1, pr1, pi1, p61r, p61i);
    // ---- packed inverse FFT of (C[t], C[t+1]) -> frames (t+1, t+2) ----
    if (t >= tprod - 2) {
      float izr[8], izi[8];
      #pragma unroll
      for (int c = 0; c < 8; ++c) {
        int k = 64 * c + lane;
        bool mir = (k > 256);
        int idx = mir ? (512 - k) : k;
        float2 a = Lc0[PDK(idx)];
        float2 b = Lc1[PDK(idx)];
        float ay = mir ? -a.y : a.y;
        float by = mir ?  b.y : -b.y;
        izr[c] = sc * (a.x + by);
        izi[c] = sc * (b.x + ay);
      }
      fft512_regs<-1>(izr, izi, lane);
      const int fa = t + 1;
      int fb = t + 2; int nfb = (fb > N_ITER - 1) ? (N_ITER - 1) : fb;
      const float efa = env[fa];  const float efa2 = efa * efa;
      const float efb = env[nfb]; const float efb2 = efb * efb;
      const float* na_ = noise + (size_t)fa  * BLOCK_N + base;
      const float* nb_ = noise + (size_t)nfb * BLOCK_N + base;
      float Aa[8], Bb[8];
      *(float4*)(&Aa[0]) = *(const float4*)(na_);
      *(float4*)(&Aa[4]) = *(const float4*)(na_ + 4);
      *(float4*)(&Bb[0]) = *(const float4*)(nb_);
      *(float4*)(&Bb[4]) = *(const float4*)(nb_ + 4);
      float va[8], vb[8];
      #pragma unroll
      for (int s = 0; s < 8; ++s) {
        int c = CB3[s];
        va[s] = izr[c] + (2.f * Aa[s] - 1.f) * efa2;
        vb[s] = izi[c] + (2.f * Bb[s] - 1.f) * efb2;
      }
      // Half-merge exchanges via DPP xor1 (VALU).
      float sva[8], spv[8];
      #pragma unroll
      for (int s = 0; s < 8; ++s) {
        sva[s] = dppq<DPP_XOR1>(va[s]);
        spv[s] = dppq<DPP_XOR1>(pvb[s]);
      }
      if (!(lane & 1)) {
        if (t >= tprod) {                       // row fa = va lower + pvb upper
          float* o = out + (size_t)fa * 256 + base;
          ((float4*)o)[0] = make_float4(va[0]+spv[0], va[1]+spv[1], va[2]+spv[2], va[3]+spv[3]);
          ((float4*)o)[1] = make_float4(va[4]+spv[4], va[5]+spv[5], va[6]+spv[6], va[7]+spv[7]);
        }
        if (fb <= tprod + 7) {                  // row fb = vb lower + va upper
          float* o = out + (size_t)fb * 256 + base;
          ((float4*)o)[0] = make_float4(vb[0]+sva[0], vb[1]+sva[1], vb[2]+sva[2], vb[3]+sva[3]);
          ((float4*)o)[1] = make_float4(vb[4]+sva[4], vb[5]+sva[5], vb[6]+sva[6], vb[7]+sva[7]);
        }
      }
      #pragma unroll
      for (int s = 0; s < 8; ++s) pvb[s] = vb[s];
    }
  }
#undef LOADTF
#undef LOADNOISE
#undef STEP
}

extern "C" void kernel_launch(void* const* d_in, const int* in_sizes, int n_in,
                              void* d_out, int out_size, void* d_ws, size_t ws_size,
                              hipStream_t stream) {
  (void)in_sizes; (void)n_in; (void)ws_size; (void)out_size; (void)d_ws;
  const float* noise = (const float*)d_in[1];
  const float* env   = (const float*)d_in[2];
  const float* tfr   = (const float*)d_in[3];
  const float* tfi   = (const float*)d_in[4];
  float* out = (float*)d_out;
  // Single fused kernel; no workspace needed (every out row fully written).
  ks_mega<<<dim3(NCHUNK / 4), dim3(256), 0, stream>>>(noise, env, tfr, tfi, out);
}

// Round 10
// 209.569 us; speedup vs baseline: 2.3933x; 1.0053x over previous
//
#include <hip/hip_runtime.h>
#include <math.h>

// ---------------------------------------------------------------------------
// KarplusStrong, fully fused single kernel (R10-verified structure).
//   C_t = Wconv3( tf_t ⊙ (C_{t-1} + P_t) ),  P_t = rfft(imps_t)  (spectral
//   recurrence, 3-tap hamming conv, Im=0 at bins 0,256). Contraction =>
//   warmup per 8-frame chunk.
//
// R18 == R17 resubmitted verbatim (R17 bench died on infra: "container
// failed twice"; no signal to learn from).
//
// R17: R15 (warmup-4, best passing @210.7us) + s_setprio around FFT bodies.
//  - R16 post-mortem: warmup-2 FAILED absmax 0.0469 > 0.0409 (measured
//    2-step contraction residual ~0.08 relative). Warmup-3 impossible
//    (pair parity). Warmup lever exhausted at 4 -> REVERTED to R15.
//  - setprio(1) during FFT compute: waves here are unsynchronized (no
//    barriers, private LDS slices) — the regime where setprio measured
//    +4-7% (attn m191) vs null in lockstep GEMM (m190). A wave in its
//    VALU-dense FFT gets issue preference over waves in DS-wait.
//    Zero correctness risk (pure scheduler hint).
// ---------------------------------------------------------------------------

#define N_ITER   32768
#define NBINS    257
#define BLOCK_N  512
#define FCH      8
#define NCHUNK   (N_ITER / FCH)     // 4096 waves
#define OUT_LEN  8388608

__device__ __forceinline__ int brev6(int x) { return (int)(__brev((unsigned)x) >> 26); }
__device__ __forceinline__ int PDK(int k) { return k + (k >> 3); }
#define PLDSZ 289

// DPP exchange (VALU, not LDS pipe). CTRL=0xB1: lane^1 (quad_perm);
// 0x4E: lane^2 (quad_perm); 0x128: row_ror:8 == lane^8 within 16-lane rows.
template<int CTRL>
__device__ __forceinline__ float dppq(float x) {
  union { float f; int i; } u; u.f = x;
  u.i = __builtin_amdgcn_update_dpp(u.i, u.i, CTRL, 0xF, 0xF, false);
  return u.f;
}
#define DPP_XOR1 0xB1
#define DPP_XOR2 0x4E
#define DPP_XOR8 0x128

// gfx950 VALU half-wave swaps: partner value z[lane^32] / z[lane^16].
// v_permlane32_swap_b32 returns r[0]=new-vdst={x_lo,x_lo},
// r[1]=new-vsrc={x_hi,x_hi}; partner: lo lanes take r[1], hi take r[0].
__device__ __forceinline__ float pswap32(float x, int lane) {
#if __has_builtin(__builtin_amdgcn_permlane32_swap)
  typedef unsigned v2u __attribute__((ext_vector_type(2)));
  union { float f; unsigned u; } v; v.f = x;
  v2u r = __builtin_amdgcn_permlane32_swap(v.u, v.u, false, false);
  union { unsigned u; float f; } o; o.u = (lane & 32) ? r[0] : r[1];
  return o.f;
#else
  return __shfl_xor(x, 32, 64);
#endif
}
// v_permlane16_swap_b32: r[0] rows={x0,x0,x2,x2}, r[1] rows={x1,x1,x3,x3}.
// Partner x[lane^16]: rows 0,2 take r[1]; rows 1,3 take r[0].
__device__ __forceinline__ float pswap16(float x, int lane) {
#if __has_builtin(__builtin_amdgcn_permlane16_swap)
  typedef unsigned v2u __attribute__((ext_vector_type(2)));
  union { float f; unsigned u; } v; v.f = x;
  v2u r = __builtin_amdgcn_permlane16_swap(v.u, v.u, false, false);
  union { unsigned u; float f; } o; o.u = (lane & 16) ? r[0] : r[1];
  return o.f;
#else
  return __shfl_xor(x, 16, 64);
#endif
}

// 512-pt complex DIF FFT across one wave: reg c, lane l <-> position 64c+l.
// Natural-order input; output at position i holds X[brev9(i)].
// TS=+1: forward (e^-i); TS=-1: inverse kernel (e^+i), unnormalized.
template<int TS>
__device__ __forceinline__ void fft512_regs(float (&zr)[8], float (&zi)[8], int lane) {
  const float ts = (float)TS;
  float s1, c1;
  __sincosf((float)lane * (3.14159265358979323846f / 256.0f), &s1, &c1);
  const float v1r = c1, v1i = -ts * s1;            // e^{-i ts pi l/256}
  const float SQ = 0.70710678118654752f;
  {
    const float r4r[4] = {1.f, SQ, 0.f, -SQ};
    const float r4i[4] = {0.f, -ts*SQ, -ts, -ts*SQ};
    #pragma unroll
    for (int c = 0; c < 4; ++c) {
      float twr = v1r*r4r[c] - v1i*r4i[c];
      float twi = v1r*r4i[c] + v1i*r4r[c];
      float ar = zr[c], ai = zi[c], br = zr[c+4], bi = zi[c+4];
      zr[c] = ar + br; zi[c] = ai + bi;
      float dr = ar - br, di = ai - bi;
      zr[c+4] = dr*twr - di*twi; zi[c+4] = dr*twi + di*twr;
    }
  }
  const float v2r = v1r*v1r - v1i*v1i, v2i = 2.f*v1r*v1i;
  #pragma unroll
  for (int c0 = 0; c0 < 8; c0 += 4) {
    #pragma unroll
    for (int cc = 0; cc < 2; ++cc) {
      int c = c0 + cc;
      float ar = zr[c], ai = zi[c], br = zr[c+2], bi = zi[c+2];
      zr[c] = ar + br; zi[c] = ai + bi;
      float dr = ar - br, di = ai - bi;
      float qr = dr*v2r - di*v2i, qi = dr*v2i + di*v2r;
      if (cc) { float t_ = qr; qr = ts*qi; qi = -ts*t_; }
      zr[c+2] = qr; zi[c+2] = qi;
    }
  }
  float wr = v2r*v2r - v2i*v2i, wi = 2.f*v2r*v2i;
  #pragma unroll
  for (int c = 0; c < 8; c += 2) {
    float ar = zr[c], ai = zi[c], br = zr[c+1], bi = zi[c+1];
    zr[c] = ar + br; zi[c] = ai + bi;
    float dr = ar - br, di = ai - bi;
    zr[c+1] = dr*wr - di*wi; zi[c+1] = dr*wi + di*wr;
  }
  // lane stages m=32..4: chain w; twiddle is -w on hi lanes, so
  // out_hi = (x_hi - x_lo)*w.  m=32/16 via permlane*_swap (VALU),
  // m=8 via DPP row_ror:8 (VALU), m=4 via shuffle (DS pipe).
#define LANE_STAGE(MBIT, EXCH)                                                 \
  {                                                                            \
    float nwr = wr*wr - wi*wi, nwi = 2.f*wr*wi;                                \
    wr = nwr; wi = nwi;                                                        \
    _Pragma("unroll")                                                          \
    for (int c = 0; c < 8; ++c) {                                              \
      float pr_ = EXCH(zr[c]);                                                 \
      float pi_ = EXCH(zi[c]);                                                 \
      bool hi = (lane & (MBIT)) != 0;                                          \
      float sr_ = zr[c] + pr_, si_ = zi[c] + pi_;                              \
      float dr = zr[c] - pr_, di = zi[c] - pi_;                                \
      float qr = dr*wr - di*wi, qi = dr*wi + di*wr;                            \
      zr[c] = hi ? qr : sr_;                                                   \
      zi[c] = hi ? qi : si_;                                                   \
    }                                                                          \
  }
#define EX32(x) pswap32((x), lane)
#define EX16(x) pswap16((x), lane)
#define EX8(x)  dppq<DPP_XOR8>(x)
#define EX4(x)  __shfl_xor((x), 4, 64)
  LANE_STAGE(32, EX32)
  LANE_STAGE(16, EX16)
  LANE_STAGE(8,  EX8)
  LANE_STAGE(4,  EX4)
#undef LANE_STAGE
#undef EX32
#undef EX16
#undef EX8
#undef EX4
  // ---- stage m=2 via DPP quad_perm (xor2) ----
  {
    float nwr = wr*wr - wi*wi, nwi = 2.f*wr*wi;
    wr = nwr; wi = nwi;
    #pragma unroll
    for (int c = 0; c < 8; ++c) {
      float pr_ = dppq<DPP_XOR2>(zr[c]);
      float pi_ = dppq<DPP_XOR2>(zi[c]);
      bool hi = (lane & 2) != 0;
      float sr_ = zr[c] + pr_, si_ = zi[c] + pi_;
      float dr = zr[c] - pr_, di = zi[c] - pi_;
      float qr = dr*wr - di*wi, qi = dr*wi + di*wr;
      zr[c] = hi ? qr : sr_;
      zi[c] = hi ? qi : si_;
    }
  }
  // ---- stage m=1 via DPP quad_perm (xor1), tw = 1 ----
  #pragma unroll
  for (int c = 0; c < 8; ++c) {
    float pr_ = dppq<DPP_XOR1>(zr[c]);
    float pi_ = dppq<DPP_XOR1>(zi[c]);
    bool hi = (lane & 1) != 0;
    zr[c] = hi ? (pr_ - zr[c]) : (zr[c] + pr_);
    zi[c] = hi ? (pi_ - zi[c]) : (zi[c] + pi_);
  }
}

__global__ __launch_bounds__(256) void ks_mega(const float* __restrict__ noise,
                                               const float* __restrict__ env,
                                               const float* __restrict__ tfr,
                                               const float* __restrict__ tfi,
                                               float* __restrict__ out) {
  __shared__ float2 Pld[4][2][PLDSZ];
  __shared__ float2 LcS[4][2][PLDSZ];
  const int w = threadIdx.x >> 6, lane = threadIdx.x & 63;
  const int j = blockIdx.x * 4 + w;
  const int k0 = lane * 4;
  const bool l63 = (lane == 63);
  const int rr = brev6(lane);
  const int base = 8 * rr;
  const int tprod = j * FCH;
  const int t0 = (j == 0) ? 0 : (tprod - 4);   // warmup 4 (R15-verified)
  const int tend = tprod + FCH;
  float2* Pw0 = &Pld[w][0][0];
  float2* Pw1 = &Pld[w][1][0];
  float2* Lc0 = &LcS[w][0][0];
  float2* Lc1 = &LcS[w][1][0];
  const float sc = 1.0f / 512.0f;
  const int CB3[8] = {0,4,2,6,1,5,3,7};

  float Cr[4] = {0.f,0.f,0.f,0.f}, Ci[4] = {0.f,0.f,0.f,0.f};
  float C256 = 0.f;
  float tr[2][4], ti[2][4];
  float t6r[2] = {0.f,0.f}, t6i[2] = {0.f,0.f};
  float nA[8], nB[8], eA, eB;
  float pvb[8] = {0.f,0.f,0.f,0.f,0.f,0.f,0.f,0.f};

  // j==0 pre-pair: frame -1 = 0, frame 0 = imps0 (zero spectrum). Emit row 0
  // (= imps0 lower half) and seed pvb with frame 0.
  if (j == 0) {
    const float e0 = env[0]; const float e02 = e0 * e0;
    const float* n0 = noise + base;
    float q[8];
    *(float4*)(&q[0]) = *(const float4*)(n0);
    *(float4*)(&q[4]) = *(const float4*)(n0 + 4);
    #pragma unroll
    for (int s = 0; s < 8; ++s) pvb[s] = (2.f * q[s] - 1.f) * e02;
    if (!(lane & 1)) {
      float* o = out + base;
      ((float4*)o)[0] = make_float4(pvb[0], pvb[1], pvb[2], pvb[3]);
      ((float4*)o)[1] = make_float4(pvb[4], pvb[5], pvb[6], pvb[7]);
    }
  }

#define LOADTF(S, TS_) do {                                                    \
    const size_t _bt = (size_t)(TS_) * NBINS;                                  \
    _Pragma("unroll") for (int _i = 0; _i < 4; ++_i) {                         \
      tr[S][_i] = tfr[_bt + k0 + _i];                                          \
      ti[S][_i] = tfi[_bt + k0 + _i];                                          \
    }                                                                          \
    if (l63) { t6r[S] = tfr[_bt + 256]; t6i[S] = tfi[_bt + 256]; }             \
  } while (0)

#define LOADNOISE(TA, TB) do {                                                 \
    const float* _pa = noise + (size_t)(TA) * BLOCK_N;                         \
    const float* _pb = noise + (size_t)(TB) * BLOCK_N;                         \
    _Pragma("unroll") for (int _c = 0; _c < 8; ++_c) {                         \
      nA[_c] = _pa[64*_c + lane];                                              \
      nB[_c] = _pb[64*_c + lane];                                              \
    }                                                                          \
    eA = env[TA]; eB = env[TB];                                                \
  } while (0)

// One recurrence step; stash C_t to LDS (recur layout) when it will feed an
// inverse FFT (t >= tprod-2).
#define STEP(S, T, PR, PI, P6R, P6I) do {                                      \
    const int _t = (T);                                                        \
    float Vr[4], Vi[4];                                                        \
    _Pragma("unroll") for (int _i = 0; _i < 4; ++_i) {                         \
      float Ur = Cr[_i] + PR[_i], Ui = Ci[_i] + PI[_i];                        \
      Vr[_i] = tr[S][_i]*Ur - ti[S][_i]*Ui;                                    \
      Vi[_i] = tr[S][_i]*Ui + ti[S][_i]*Ur;                                    \
    }                                                                          \
    if (lane == 0) Vi[0] = 0.f;                                                \
    float U6r = C256 + P6R, U6i = P6I;                                         \
    float V6r = t6r[S]*U6r - t6i[S]*U6i;                                       \
    int _tf = _t + 2; if (_tf > N_ITER - 1) _tf = N_ITER - 1;                  \
    LOADTF(S, _tf);                                                            \
    float Lr = __shfl_up(Vr[3], 1),   Li = __shfl_up(Vi[3], 1);                \
    float Rr = __shfl_down(Vr[0], 1), Ri = __shfl_down(Vi[0], 1);              \
    if (lane == 0) { Lr = Vr[1]; Li = -Vi[1]; }                                \
    if (l63)       { Rr = V6r;   Ri = 0.f; }                                   \
    Cr[0] = 0.54f*Vr[0] - 0.23f*(Lr    + Vr[1]);                               \
    Ci[0] = 0.54f*Vi[0] - 0.23f*(Li    + Vi[1]);                               \
    Cr[1] = 0.54f*Vr[1] - 0.23f*(Vr[0] + Vr[2]);                               \
    Ci[1] = 0.54f*Vi[1] - 0.23f*(Vi[0] + Vi[2]);                               \
    Cr[2] = 0.54f*Vr[2] - 0.23f*(Vr[1] + Vr[3]);                               \
    Ci[2] = 0.54f*Vi[2] - 0.23f*(Vi[1] + Vi[3]);                               \
    Cr[3] = 0.54f*Vr[3] - 0.23f*(Vr[2] + Rr);                                  \
    Ci[3] = 0.54f*Vi[3] - 0.23f*(Vi[2] + Ri);                                  \
    C256  = 0.54f*V6r   - 0.46f*Vr[3];                                         \
    if (_t >= tprod - 2) {                                                     \
      float2* _Ls = ((_t) & 1) ? Lc1 : Lc0;                                    \
      _Ls[PDK(k0 + 0)] = make_float2(Cr[0], Ci[0]);                            \
      _Ls[PDK(k0 + 1)] = make_float2(Cr[1], Ci[1]);                            \
      _Ls[PDK(k0 + 2)] = make_float2(Cr[2], Ci[2]);                            \
      _Ls[PDK(k0 + 3)] = make_float2(Cr[3], Ci[3]);                            \
      if (l63) _Ls[PDK(256)] = make_float2(C256, 0.f);                         \
    }                                                                          \
  } while (0)

  LOADTF(0, t0);
  LOADTF(1, t0 + 1);
  LOADNOISE(t0, t0 + 1);

  for (int t = t0; t < tend; t += 2) {
    // ---- packed forward FFT of impulses (t, t+1) ----
    const float ea2 = eA * eA, eb2 = eB * eB;
    float zr[8], zi[8];
    #pragma unroll
    for (int c = 0; c < 8; ++c) {
      zr[c] = (2.f * nA[c] - 1.f) * ea2;
      zi[c] = (2.f * nB[c] - 1.f) * eb2;
    }
    {
      int ta = t + 2; if (ta > N_ITER - 1) ta = N_ITER - 1;
      int tb = t + 3; if (tb > N_ITER - 1) tb = N_ITER - 1;
      LOADNOISE(ta, tb);
    }
    __builtin_amdgcn_s_setprio(1);
    fft512_regs<1>(zr, zi, lane);
    __builtin_amdgcn_s_setprio(0);
    float mr[8], mi[8];
    {
      int r_ = brev6(lane);
      int lam = brev6((64 - r_) & 63);
      mr[0] = __shfl(zr[0], lam, 64); mi[0] = __shfl(zi[0], lam, 64);
    }
    mr[1] = __shfl_xor(zr[1], 63, 64); mi[1] = __shfl_xor(zi[1], 63, 64);
    mr[2] = __shfl_xor(zr[3], 63, 64); mi[2] = __shfl_xor(zi[3], 63, 64);
    mr[3] = __shfl_xor(zr[2], 63, 64); mi[3] = __shfl_xor(zi[2], 63, 64);
    mr[4] = __shfl_xor(zr[7], 63, 64); mi[4] = __shfl_xor(zi[7], 63, 64);
    mr[5] = __shfl_xor(zr[6], 63, 64); mi[5] = __shfl_xor(zi[6], 63, 64);
    mr[6] = __shfl_xor(zr[5], 63, 64); mi[6] = __shfl_xor(zi[5], 63, 64);
    mr[7] = __shfl_xor(zr[4], 63, 64); mi[7] = __shfl_xor(zi[4], 63, 64);
    if (!(lane & 1)) {
      #pragma unroll
      for (int s = 0; s < 8; ++s) {
        int c = CB3[s];
        int k = 8 * rr + s;
        Pw0[PDK(k)] = make_float2(0.5f*(zr[c] + mr[c]), 0.5f*(zi[c] - mi[c]));
        Pw1[PDK(k)] = make_float2(0.5f*(zi[c] + mi[c]), 0.5f*(mr[c] - zr[c]));
      }
    } else if (lane == 1) {
      Pw0[PDK(256)] = make_float2(0.5f*(zr[0] + mr[0]), 0.5f*(zi[0] - mi[0]));
      Pw1[PDK(256)] = make_float2(0.5f*(zi[0] + mi[0]), 0.5f*(mr[0] - zr[0]));
    }
    float pr0[4], pi0[4], pr1[4], pi1[4];
    float p60r = 0.f, p60i = 0.f, p61r = 0.f, p61i = 0.f;
    #pragma unroll
    for (int i = 0; i < 4; ++i) {
      float2 q0 = Pw0[PDK(k0 + i)];
      float2 q1 = Pw1[PDK(k0 + i)];
      pr0[i] = q0.x; pi0[i] = q0.y;
      pr1[i] = q1.x; pi1[i] = q1.y;
    }
    if (l63) {
      float2 q0 = Pw0[PDK(256)]; p60r = q0.x; p60i = q0.y;
      float2 q1 = Pw1[PDK(256)]; p61r = q1.x; p61i = q1.y;
    }
    // ---- two recurrence steps (stash C to LDS when inv-active) ----
    STEP(0, t,     pr0, pi0, p60r, p60i);
    STEP(1, t + 1, pr1, pi1, p61r, p61i);
    // ---- packed inverse FFT of (C[t], C[t+1]) -> frames (t+1, t+2) ----
    if (t >= tprod - 2) {
      float izr[8], izi[8];
      #pragma unroll
      for (int c = 0; c < 8; ++c) {
        int k = 64 * c + lane;
        bool mir = (k > 256);
        int idx = mir ? (512 - k) : k;
        float2 a = Lc0[PDK(idx)];
        float2 b = Lc1[PDK(idx)];
        float ay = mir ? -a.y : a.y;
        float by = mir ?  b.y : -b.y;
        izr[c] = sc * (a.x + by);
        izi[c] = sc * (b.x + ay);
      }
      __builtin_amdgcn_s_setprio(1);
      fft512_regs<-1>(izr, izi, lane);
      __builtin_amdgcn_s_setprio(0);
      const int fa = t + 1;
      int fb = t + 2; int nfb = (fb > N_ITER - 1) ? (N_ITER - 1) : fb;
      const float efa = env[fa];  const float efa2 = efa * efa;
      const float efb = env[nfb]; const float efb2 = efb * efb;
      const float* na_ = noise + (size_t)fa  * BLOCK_N + base;
      const float* nb_ = noise + (size_t)nfb * BLOCK_N + base;
      float Aa[8], Bb[8];
      *(float4*)(&Aa[0]) = *(const float4*)(na_);
      *(float4*)(&Aa[4]) = *(const float4*)(na_ + 4);
      *(float4*)(&Bb[0]) = *(const float4*)(nb_);
      *(float4*)(&Bb[4]) = *(const float4*)(nb_ + 4);
      float va[8], vb[8];
      #pragma unroll
      for (int s = 0; s < 8; ++s) {
        int c = CB3[s];
        va[s] = izr[c] + (2.f * Aa[s] - 1.f) * efa2;
        vb[s] = izi[c] + (2.f * Bb[s] - 1.f) * efb2;
      }
      // Half-merge exchanges via DPP xor1 (VALU).
      float sva[8], spv[8];
      #pragma unroll
      for (int s = 0; s < 8; ++s) {
        sva[s] = dppq<DPP_XOR1>(va[s]);
        spv[s] = dppq<DPP_XOR1>(pvb[s]);
      }
      if (!(lane & 1)) {
        if (t >= tprod) {                       // row fa = va lower + pvb upper
          float* o = out + (size_t)fa * 256 + base;
          ((float4*)o)[0] = make_float4(va[0]+spv[0], va[1]+spv[1], va[2]+spv[2], va[3]+spv[3]);
          ((float4*)o)[1] = make_float4(va[4]+spv[4], va[5]+spv[5], va[6]+spv[6], va[7]+spv[7]);
        }
        if (fb <= tprod + 7) {                  // row fb = vb lower + va upper
          float* o = out + (size_t)fb * 256 + base;
          ((float4*)o)[0] = make_float4(vb[0]+sva[0], vb[1]+sva[1], vb[2]+sva[2], vb[3]+sva[3]);
          ((float4*)o)[1] = make_float4(vb[4]+sva[4], vb[5]+sva[5], vb[6]+sva[6], vb[7]+sva[7]);
        }
      }
      #pragma unroll
      for (int s = 0; s < 8; ++s) pvb[s] = vb[s];
    }
  }
#undef LOADTF
#undef LOADNOISE
#undef STEP
}

extern "C" void kernel_launch(void* const* d_in, const int* in_sizes, int n_in,
                              void* d_out, int out_size, void* d_ws, size_t ws_size,
                              hipStream_t stream) {
  (void)in_sizes; (void)n_in; (void)ws_size; (void)out_size; (void)d_ws;
  const float* noise = (const float*)d_in[1];
  const float* env   = (const float*)d_in[2];
  const float* tfr   = (const float*)d_in[3];
  const float* tfi   = (const float*)d_in[4];
  float* out = (float*)d_out;
  // Single fused kernel; no workspace needed (every out row fully written).
  ks_mega<<<dim3(NCHUNK / 4), dim3(256), 0, stream>>>(noise, env, tfr, tfi, out);
}